// Round 17
// baseline (350.119 us; speedup 1.0000x reference)
//
#include <hip/hip_runtime.h>
#include <math.h>

// Dims: V=50000 F=300 H=256 P=128 C=10  B=128 S=16 N=64  G=2048 T=131072

typedef unsigned short u16;
typedef __attribute__((ext_vector_type(8))) short bf16x8;
typedef __attribute__((ext_vector_type(4))) float f32x4;

__device__ __forceinline__ float b2f(u16 v){ return __uint_as_float(((unsigned)v)<<16); }
__device__ __forceinline__ u16 f2b(float f){
    unsigned u = __float_as_uint(f);
    return (u16)((u + 0x7FFFu + ((u>>16)&1u)) >> 16);   // RNE
}
__device__ __forceinline__ ushort4 pack4(float a,float b,float c,float d){
    ushort4 o; o.x=f2b(a); o.y=f2b(b); o.z=f2b(c); o.w=f2b(d); return o;
}

// Per-graph LDS = 64 KB = two 32 KB regions that PING-PONG between phases
// (r15 scheme). Region-relative layouts (XOR-swizzled):
__device__ __forceinline__ int srow_rb(int nd, int f){
    return (nd*512 + f*2) ^ ((nd&7)<<4);
}
__device__ __forceinline__ int scol_rb(int f, int nd){
    return (f*128 + nd*2) ^ ((f&7)<<4);
}
// weight fragment offset (u16): chunk-select (ni>>1)*1024, half (ni&1)*512
__device__ __forceinline__ int wfrag_off(int ni){
    return ((ni>>1)<<10) + ((ni&1)<<9);
}

// ---------------------------------------------------------------------------
// Megakernel: 1024 blocks x 512 threads; block = TWO graphs.
// r17: S3/S4 use FEATURE-split (M-split) serial passes -- each weight
// fragment is loaded exactly once across both passes (r15's node-split
// reloaded all 4 per pass => 2x L2 weight traffic). S4's logits accumulate
// across passes in persistent lgt[4][4]. Serial passes (#pragma unroll 1)
// keep one acc[.][.] (32 regs) live (r14 lesson: unroll merges liveness).
// ---------------------------------------------------------------------------
__global__ __launch_bounds__(512, 1) void mega_k(
    const int* __restrict__ x, const u16* __restrict__ adjb,
    const u16* __restrict__ eprime,
    const u16* __restrict__ wb_w2a, const u16* __restrict__ wb_awa,
    const u16* __restrict__ wb_w1b, const u16* __restrict__ wb_w2b,
    const u16* __restrict__ wb_awb,
    const float* __restrict__ b1a, const float* __restrict__ b2a,
    const float* __restrict__ aba, const float* __restrict__ ava,
    const float* __restrict__ b1b, const float* __restrict__ b2b,
    const float* __restrict__ abb, const float* __restrict__ avb,
    u16* __restrict__ zb)
{
    __shared__ __align__(16) char sm[131072];
    const int tid = threadIdx.x;
    const int w = tid>>6, l = tid&63, lgp = l>>4, ll = l&15;
    const int q = w>>2, w4 = w&3, slab = w4*64;
    const long g = (long)blockIdx.x*2 + q;
    char* smq = sm + q*65536;
    const f32x4 zero4 = {0.f,0.f,0.f,0.f};

    // ---------------- S1: gather E'[x] rows for BOTH graphs -> scol @ R1
    {
        const int r2 = tid >> 3;           // node 0..63
        const int fc = (tid & 7) * 32;     // 32-feature chunk
        #pragma unroll
        for (int q2=0; q2<2; ++q2){
            const u16* ep = eprime + (long)x[((long)blockIdx.x*2+q2)*64 + r2]*256 + fc;
            char* smr = sm + q2*65536 + 32768;
            uint4 qa = *(const uint4*)(ep);
            uint4 qb = *(const uint4*)(ep + 8);
            uint4 qc = *(const uint4*)(ep + 16);
            uint4 qd = *(const uint4*)(ep + 24);
            #pragma unroll
            for (int qi=0; qi<4; ++qi){
                uint4 v = (qi==0)?qa:(qi==1)?qb:(qi==2)?qc:qd;
                unsigned xw[4] = {v.x, v.y, v.z, v.w};
                #pragma unroll
                for (int wi=0; wi<4; ++wi){
                    unsigned u = xw[wi];
                    int f0 = fc + qi*8 + wi*2;
                    *(u16*)(smr + scol_rb(f0,   r2)) = (u16)(u & 0xffffu);
                    *(u16*)(smr + scol_rb(f0+1, r2)) = (u16)(u >> 16);
                }
            }
        }
        __syncthreads();
    }

    const u16* adjg = adjb + g*4096;

    // ========== layer loop ==========
    #pragma unroll 1
    for (int layer=0; layer<2; ++layer){
        const u16* wb_w2 = layer ? wb_w2b : wb_w2a;
        const u16* wb_aw = layer ? wb_awb : wb_awa;
        const float* b1  = layer ? b1b : b1a;
        const float* b2  = layer ? b2b : b2a;
        const float* ab  = layer ? abb : aba;
        const float* av  = layer ? avb : ava;
        const int zoff   = layer ? 512 : 0;
        const int pA = layer ? 0 : 32768;
        const int pB = layer ? 32768 : 0;

        // ---------- S2: T = relu(adj @ P + b1): scol@pA -> srow@pB (node-split)
        #pragma unroll 1
        for (int nh=0; nh<2; ++nh){
            f32x4 acc[4][2];
            #pragma unroll
            for (int i=0;i<4;++i){ acc[i][0] = zero4; acc[i][1] = zero4; }
            #pragma unroll
            for (int t=0;t<2;++t){
                const int k0 = t*32 + lgp*8;
                bf16x8 a[4], b[2];
                #pragma unroll
                for (int mi=0;mi<4;++mi)
                    a[mi] = *(const bf16x8*)(smq + pA + scol_rb(slab + mi*16 + ll, k0));
                #pragma unroll
                for (int ni=0;ni<2;++ni)
                    b[ni] = *(const bf16x8*)(adjg + ((nh*2+ni)*16+ll)*64 + k0);
                #pragma unroll
                for (int mi=0;mi<4;++mi){
                    acc[mi][0] = __builtin_amdgcn_mfma_f32_16x16x32_bf16(a[mi], b[0], acc[mi][0],0,0,0);
                    acc[mi][1] = __builtin_amdgcn_mfma_f32_16x16x32_bf16(a[mi], b[1], acc[mi][1],0,0,0);
                }
            }
            #pragma unroll
            for (int mi=0;mi<4;++mi){
                int f0 = slab + mi*16 + lgp*4;
                float4 bi = *(const float4*)(b1 + f0);
                #pragma unroll
                for (int ni=0;ni<2;++ni){
                    int nd = (nh*2+ni)*16 + ll;
                    f32x4 v = acc[mi][ni];
                    *(ushort4*)(smq + pB + srow_rb(nd, f0)) = pack4(
                        fmaxf(v[0]+bi.x,0.f), fmaxf(v[1]+bi.y,0.f),
                        fmaxf(v[2]+bi.z,0.f), fmaxf(v[3]+bi.w,0.f));
                }
            }
        }
        __syncthreads();

        // ---------- S3: H = relu(T @ w2 + b2): srow@pB -> srow@pA
        // FEATURE-split: pass fh loads only cw(fh*2),cw(fh*2+1); b re-read from LDS.
        #pragma unroll 1
        for (int fh=0; fh<2; ++fh){
            f32x4 acc[2][4];
            #pragma unroll
            for (int j=0;j<4;++j){ acc[0][j] = zero4; acc[1][j] = zero4; }
            const u16* chw = wb_w2 + ((w4*2)<<10) + ll*32 + lgp*8;
            #pragma unroll
            for (int t=0;t<8;++t){
                const u16* ct = chw + t*8192;
                const int k0 = t*32 + lgp*8;
                bf16x8 cw0 = *(const bf16x8*)(ct + wfrag_off(fh*2+0));
                bf16x8 cw1 = *(const bf16x8*)(ct + wfrag_off(fh*2+1));
                bf16x8 b[4];
                #pragma unroll
                for (int ni=0;ni<4;++ni)
                    b[ni] = *(const bf16x8*)(smq + pB + srow_rb(ni*16+ll, k0));
                #pragma unroll
                for (int ni=0;ni<4;++ni){
                    acc[0][ni] = __builtin_amdgcn_mfma_f32_16x16x32_bf16(cw0, b[ni], acc[0][ni],0,0,0);
                    acc[1][ni] = __builtin_amdgcn_mfma_f32_16x16x32_bf16(cw1, b[ni], acc[1][ni],0,0,0);
                }
            }
            #pragma unroll
            for (int mi=0;mi<2;++mi){
                int f0 = slab + (fh*2+mi)*16 + lgp*4;
                float4 bi = *(const float4*)(b2 + f0);
                #pragma unroll
                for (int ni=0;ni<4;++ni){
                    int nd = ni*16 + ll;
                    f32x4 v = acc[mi][ni];
                    *(ushort4*)(smq + pA + srow_rb(nd, f0)) = pack4(
                        fmaxf(v[0]+bi.x,0.f), fmaxf(v[1]+bi.y,0.f),
                        fmaxf(v[2]+bi.z,0.f), fmaxf(v[3]+bi.w,0.f));
                }
            }
        }
        __syncthreads();

        // ---------- S4: attention: H srow@pA, scratch@pB
        // FEATURE-split passes; logits accumulate in persistent lgt[4][4].
        {
            float lgt[4][4];
            #pragma unroll
            for (int mi=0;mi<4;++mi){
                #pragma unroll
                for (int r=0;r<4;++r) lgt[mi][r] = 0.f;
            }
            #pragma unroll 1
            for (int fh=0; fh<2; ++fh){
                f32x4 acc[4][2];
                #pragma unroll
                for (int i=0;i<4;++i){ acc[i][0] = zero4; acc[i][1] = zero4; }
                const u16* chw = wb_aw + ((w4*2)<<10) + ll*32 + lgp*8;
                #pragma unroll
                for (int t=0;t<8;++t){
                    const u16* ct = chw + t*8192;
                    const int k0 = t*32 + lgp*8;
                    bf16x8 cw0 = *(const bf16x8*)(ct + wfrag_off(fh*2+0));
                    bf16x8 cw1 = *(const bf16x8*)(ct + wfrag_off(fh*2+1));
                    bf16x8 a[4];
                    #pragma unroll
                    for (int mi=0;mi<4;++mi)
                        a[mi] = *(const bf16x8*)(smq + pA + srow_rb(mi*16+ll, k0));
                    #pragma unroll
                    for (int mi=0;mi<4;++mi){
                        acc[mi][0] = __builtin_amdgcn_mfma_f32_16x16x32_bf16(a[mi], cw0, acc[mi][0],0,0,0);
                        acc[mi][1] = __builtin_amdgcn_mfma_f32_16x16x32_bf16(a[mi], cw1, acc[mi][1],0,0,0);
                    }
                }
                float ab0 = ab[slab + (fh*2+0)*16 + ll], av0 = av[slab + (fh*2+0)*16 + ll];
                float ab1 = ab[slab + (fh*2+1)*16 + ll], av1 = av[slab + (fh*2+1)*16 + ll];
                #pragma unroll
                for (int mi=0;mi<4;++mi){
                    f32x4 v0 = acc[mi][0], v1 = acc[mi][1];
                    #pragma unroll
                    for (int r=0;r<4;++r){
                        lgt[mi][r] += fmaxf(v0[r]+ab0,0.f)*av0
                                    + fmaxf(v1[r]+ab1,0.f)*av1;
                    }
                }
            }
            #pragma unroll
            for (int mi=0;mi<4;++mi){
                #pragma unroll
                for (int r=0;r<4;++r){
                    float vv = lgt[mi][r];
                    vv += __shfl_xor(vv,1,64); vv += __shfl_xor(vv,2,64);
                    vv += __shfl_xor(vv,4,64); vv += __shfl_xor(vv,8,64);
                    lgt[mi][r] = vv;
                }
            }
            float* red = (float*)(smq + pB);
            if (ll == 0){
                #pragma unroll
                for (int mi=0;mi<4;++mi){
                    #pragma unroll
                    for (int r=0;r<4;++r){
                        int node = mi*16 + lgp*4 + r;
                        red[w4*64 + node] = lgt[mi][r];
                    }
                }
            }
            __syncthreads();
            if (tid < 128){
                int qs = tid >> 6, t64 = tid & 63;
                const float* rq = (const float*)(sm + qs*65536 + pB);
                float lv = rq[t64] + rq[64+t64] + rq[128+t64] + rq[192+t64];
                float v = (t64 < 63) ? lv : -INFINITY;
                float m = v;
                #pragma unroll
                for (int off=32; off; off>>=1) m = fmaxf(m, __shfl_xor(m, off, 64));
                float e = (t64 < 63) ? expf(v - m) : 0.f;
                float s = e;
                #pragma unroll
                for (int off=32; off; off>>=1) s += __shfl_xor(s, off, 64);
                *(float*)(sm + qs*65536 + pB + 1024 + t64*4) = e / s;
            }
            __syncthreads();
            {
                int qs = tid >> 8, c = tid & 255;
                char* smr = sm + qs*65536;
                const float* alpha = (const float*)(smr + pB + 1024);
                float pool = 0.f;
                for (int r=0;r<63;++r)
                    pool += alpha[r]*b2f(*(const u16*)(smr + pA + srow_rb(r,c)));
                long zb0 = ((long)blockIdx.x*2 + qs)*1024 + zoff;
                zb[zb0 + c]       = f2b(pool);
                zb[zb0 + 256 + c] = *(const u16*)(smr + pA + srow_rb(63,c));
            }
            __syncthreads();
        }

        // ---------- S5 (layer 0 only): P1 = H @ w1b: srow@pA -> scol@pB
        if (layer == 0){
            #pragma unroll 1
            for (int nh=0; nh<2; ++nh){
                f32x4 acc[4][2];
                #pragma unroll
                for (int i=0;i<4;++i){ acc[i][0] = zero4; acc[i][1] = zero4; }
                const u16* chw = wb_w1b + ((w4*2)<<10) + ll*32 + lgp*8;
                #pragma unroll
                for (int t=0;t<8;++t){
                    const u16* ct = chw + t*8192;
                    const int k0 = t*32 + lgp*8;
                    bf16x8 cwA = *(const bf16x8*)(ct + wfrag_off(nh*2+0));
                    bf16x8 cwB = *(const bf16x8*)(ct + wfrag_off(nh*2+1));
                    bf16x8 a[4];
                    #pragma unroll
                    for (int mi=0;mi<4;++mi)
                        a[mi] = *(const bf16x8*)(smq + pA + srow_rb(mi*16+ll, k0));
                    #pragma unroll
                    for (int mi=0;mi<4;++mi){
                        acc[mi][0] = __builtin_amdgcn_mfma_f32_16x16x32_bf16(a[mi], cwA, acc[mi][0],0,0,0);
                        acc[mi][1] = __builtin_amdgcn_mfma_f32_16x16x32_bf16(a[mi], cwB, acc[mi][1],0,0,0);
                    }
                }
                #pragma unroll
                for (int mi=0;mi<4;++mi){
                    #pragma unroll
                    for (int ni=0;ni<2;++ni){
                        int fo = slab + (nh*2+ni)*16 + ll, nd0 = mi*16 + lgp*4;
                        f32x4 v = acc[mi][ni];
                        *(ushort4*)(smq + pB + scol_rb(fo,nd0)) = pack4(v[0],v[1],v[2],v[3]);
                    }
                }
            }
            __syncthreads();
        }
    }
}

// ---------------------------------------------------------------------------
// E' = emb @ w1a  (50000x300 @ 300x256 -> bf16 50000x256 row-major).
// 512-thread blocks covering all 256 cols (grid 1563) -> emb read once.
// ---------------------------------------------------------------------------
__global__ __launch_bounds__(512) void eprime_k(
    const float* __restrict__ emb, const u16* __restrict__ blob,
    u16* __restrict__ eprime)
{
    __shared__ __align__(16) char sm[4096];     // 2 x 2KB A-tile dbuf
    const int m0 = blockIdx.x * 32;
    const int tid = threadIdx.x;
    const int w = tid>>6, l = tid&63, lgp = l>>4, ll = l&15;
    const f32x4 zero4 = {0.f,0.f,0.f,0.f};

    const int r  = tid >> 4;          // row 0..31
    const int kf = (tid & 15) * 2;    // float-pair index within 32
    int rowg = m0 + r; if (rowg > 49999) rowg = 49999;
    const long arow = (long)rowg * 300;
    const int wbyte = (r*64 + kf*2) ^ ((r&7)<<4);

    float2 pv = (kf + 2 <= 300) ? *(const float2*)(emb + arow + kf)
                                : make_float2(0.f,0.f);
    const u16* chw = blob + (w<<10) + ll*32 + lgp*8;
    bf16x8 w0 = *(const bf16x8*)(chw);
    bf16x8 w1 = *(const bf16x8*)(chw + 512);

    f32x4 acc[2][2];
    acc[0][0]=zero4; acc[0][1]=zero4; acc[1][0]=zero4; acc[1][1]=zero4;

    #pragma unroll
    for (int t=0;t<10;++t){
        float2 cur = pv;
        bf16x8 cw0 = w0, cw1 = w1;
        if (t < 9){
            int kn = (t+1)*32 + kf;
            pv = (kn + 2 <= 300) ? *(const float2*)(emb + arow + kn)
                                 : make_float2(0.f,0.f);
            const u16* nx = chw + (t+1)*8192;
            w0 = *(const bf16x8*)(nx);
            w1 = *(const bf16x8*)(nx + 512);
        }
        ushort2 st; st.x = f2b(cur.x); st.y = f2b(cur.y);
        *(ushort2*)(sm + (t&1)*2048 + wbyte) = st;
        __syncthreads();
        const char* eb = sm + (t&1)*2048;
        bf16x8 a0, a1;
        {
            int row = ll;
            a0 = *(const bf16x8*)(eb + ((row*64 + lgp*16) ^ ((row&7)<<4)));
            row = 16 + ll;
            a1 = *(const bf16x8*)(eb + ((row*64 + lgp*16) ^ ((row&7)<<4)));
        }
        acc[0][0] = __builtin_amdgcn_mfma_f32_16x16x32_bf16(a0, cw0, acc[0][0],0,0,0);
        acc[0][1] = __builtin_amdgcn_mfma_f32_16x16x32_bf16(a0, cw1, acc[0][1],0,0,0);
        acc[1][0] = __builtin_amdgcn_mfma_f32_16x16x32_bf16(a1, cw0, acc[1][0],0,0,0);
        acc[1][1] = __builtin_amdgcn_mfma_f32_16x16x32_bf16(a1, cw1, acc[1][1],0,0,0);
        __syncthreads();
    }
    #pragma unroll
    for (int mi=0;mi<2;++mi){
        #pragma unroll
        for (int ni=0;ni<2;++ni){
            int col = w*32 + ni*16 + ll;
            f32x4 v = acc[mi][ni];
            #pragma unroll
            for (int rr=0;rr<4;++rr){
                int row = m0 + mi*16 + lgp*4 + rr;
                if (row < 50000) eprime[(long)row*256 + col] = f2b(v[rr]);
            }
        }
    }
}

// ---------------------------------------------------------------------------
// Weight pre-pass: 6 GEMM weights -> bf16 8-slab K-tiled blobs (zero-pad K).
// ---------------------------------------------------------------------------
__global__ __launch_bounds__(256) void conv_all_k(
    const float* __restrict__ w1a, const float* __restrict__ w2a,
    const float* __restrict__ awa, const float* __restrict__ w1b,
    const float* __restrict__ w2b, const float* __restrict__ awb,
    u16* __restrict__ dst_base)
{
    long idx = (long)blockIdx.x*256 + threadIdx.x;
    if (idx >= 81920L + 5L*65536L) return;
    const float* src; u16* dst; int Ksrc; long rem;
    if (idx < 81920L){ src = w1a; dst = dst_base; Ksrc = 300; rem = idx; }
    else {
        long j = (idx - 81920L) / 65536L, r2 = (idx - 81920L) % 65536L;
        src = (j==0)?w2a:(j==1)?awa:(j==2)?w1b:(j==3)?w2b:awb;
        dst = dst_base + 81920L + j*65536L; Ksrc = 256; rem = r2;
    }
    int k = (int)(rem >> 8), n = (int)(rem & 255);
    float v = (k < Ksrc) ? src[k*256 + n] : 0.f;
    int t = k>>5, kk = k&31;
    dst[((t*8 + (n>>5))<<10) + (n&31)*32 + kk] = f2b(v);
}

// adj f32 -> bf16, float4/ushort4 vectorized
__global__ __launch_bounds__(256) void adjconv_k(
    const float* __restrict__ adj, u16* __restrict__ adjb)
{
    long i = ((long)blockIdx.x*256 + threadIdx.x) * 4;
    if (i >= 2048L*4096L) return;
    float4 v = *(const float4*)(adj + i);
    *(ushort4*)(adjb + i) = pack4(v.x, v.y, v.z, v.w);
}

// ---------------------------------------------------------------------------
// BatchNorm stats over rows of zb (2048 x 1024 bf16): scale/shift per column.
// ---------------------------------------------------------------------------
__global__ __launch_bounds__(256) void bnstats_k(
    const u16* __restrict__ zb, const float* __restrict__ gamma,
    const float* __restrict__ beta,
    float* __restrict__ scale, float* __restrict__ shift)
{
    const int tid = threadIdx.x;
    const int cl = tid & 3, ph = tid >> 2;
    const int c = blockIdx.x * 4 + cl;
    double s = 0.0, s2 = 0.0;
    #pragma unroll 8
    for (int r = ph; r < 2048; r += 64) {
        float v = b2f(zb[(long)r * 1024 + c]);
        s += v; s2 += (double)v * v;
    }
    __shared__ double ss[256], ss2[256];
    ss[tid] = s; ss2[tid] = s2;
    __syncthreads();
    for (int off = 128; off >= 4; off >>= 1){
        if (tid < off){ ss[tid] += ss[tid+off]; ss2[tid] += ss2[tid+off]; }
        __syncthreads();
    }
    if (tid < 4){
        int cc = blockIdx.x * 4 + tid;
        double mu = ss[tid] / 2048.0;
        double var = ss2[tid] / 2048.0 - mu * mu;
        float inv = (float)(1.0 / sqrt(var + 1e-5));
        float sc = gamma[cc] * inv;
        scale[cc] = sc;
        shift[cc] = beta[cc] - (float)mu * sc;
    }
}

// ---------------------------------------------------------------------------
// fc1 prep (merged): blocks [0,1024) build the bn-scaled bf16 weight blob;
// blocks [1024,1280) build the fused bias.
// ---------------------------------------------------------------------------
__global__ __launch_bounds__(256) void fc1prep_k(
    const float* __restrict__ fw, const float* __restrict__ scale,
    const float* __restrict__ shift, const float* __restrict__ fb,
    u16* __restrict__ dst, float* __restrict__ biasp)
{
    if (blockIdx.x < 1024){
        int lin = blockIdx.x*256 + threadIdx.x;           // 262144 total
        int c = lin >> 10, t = c >> 3, s = c & 7;
        int nl = (lin >> 5) & 31, kk = lin & 31;
        int n = s*32 + nl, k = t*32 + kk;
        dst[lin] = f2b(fw[k*256 + n] * scale[k]);
    } else {
        const int n = blockIdx.x - 1024, tid = threadIdx.x;
        float p = 0.f;
        #pragma unroll
        for (int i=0;i<4;++i){
            int k = tid + i*256;
            p += shift[k] * fw[k*256 + n];
        }
        __shared__ float red[256];
        red[tid] = p;
        __syncthreads();
        for (int off=128; off; off>>=1){
            if (tid < off) red[tid] += red[tid+off];
            __syncthreads();
        }
        if (tid == 0) biasp[n] = fb[n] + red[0];
    }
}

// ---------------------------------------------------------------------------
// fc1 MFMA: z2 = relu(zb @ W' + biasp)  (2048x1024 @ 1024x256, bn absorbed)
// ---------------------------------------------------------------------------
__global__ __launch_bounds__(256) void fc1_mfma_k(
    const u16* __restrict__ zb, const u16* __restrict__ blob,
    const float* __restrict__ biasp, float* __restrict__ z2)
{
    __shared__ __align__(16) char sm[4096];     // 2 x 2KB A-tile dbuf
    const int h = blockIdx.x, m0 = blockIdx.y * 32;
    const int tid = threadIdx.x;
    const int w = tid>>6, l = tid&63, lgp = l>>4, ll = l&15;
    const f32x4 zero4 = {0.f,0.f,0.f,0.f};
    const int slab = h*4 + w;

    const int r  = tid >> 3;          // row 0..31
    const int kc = (tid & 7) * 4;     // k-chunk within 32
    const long arow = (long)(m0 + r) * 1024;
    const int wbyte = (r*64 + (tid&7)*8) ^ ((r&7)<<4);

    ushort4 pv = *(const ushort4*)(zb + arow + kc);
    const u16* chw = blob + (slab<<10) + ll*32 + lgp*8;
    bf16x8 w0 = *(const bf16x8*)(chw);
    bf16x8 w1 = *(const bf16x8*)(chw + 512);

    f32x4 acc[2][2];
    acc[0][0]=zero4; acc[0][1]=zero4; acc[1][0]=zero4; acc[1][1]=zero4;

    #pragma unroll 4
    for (int t=0;t<32;++t){
        ushort4 cur = pv;
        bf16x8 cw0 = w0, cw1 = w1;
        if (t < 31){
            pv = *(const ushort4*)(zb + arow + (t+1)*32 + kc);
            const u16* nx = chw + (t+1)*8192;
            w0 = *(const bf16x8*)(nx);
            w1 = *(const bf16x8*)(nx + 512);
        }
        *(ushort4*)(sm + (t&1)*2048 + wbyte) = cur;
        __syncthreads();
        const char* eb = sm + (t&1)*2048;
        bf16x8 a0, a1;
        {
            int row = ll;
            a0 = *(const bf16x8*)(eb + ((row*64 + lgp*16) ^ ((row&7)<<4)));
            row = 16 + ll;
            a1 = *(const bf16x8*)(eb + ((row*64 + lgp*16) ^ ((row&7)<<4)));
        }
        acc[0][0] = __builtin_amdgcn_mfma_f32_16x16x32_bf16(a0, cw0, acc[0][0],0,0,0);
        acc[0][1] = __builtin_amdgcn_mfma_f32_16x16x32_bf16(a0, cw1, acc[0][1],0,0,0);
        acc[1][0] = __builtin_amdgcn_mfma_f32_16x16x32_bf16(a1, cw0, acc[1][0],0,0,0);
        acc[1][1] = __builtin_amdgcn_mfma_f32_16x16x32_bf16(a1, cw1, acc[1][1],0,0,0);
        __syncthreads();
    }
    #pragma unroll
    for (int mi=0;mi<2;++mi){
        #pragma unroll
        for (int ni=0;ni<2;++ni){
            int col = h*128 + w*32 + ni*16 + ll;
            float bv = biasp[col];
            f32x4 v = acc[mi][ni];
            #pragma unroll
            for (int rr=0;rr<4;++rr){
                int row = m0 + mi*16 + lgp*4 + rr;
                z2[(long)row*256 + col] = fmaxf(v[rr] + bv, 0.f);
            }
        }
    }
}

// ---------------------------------------------------------------------------
// Segment attention + final head fused:
// z2 (128 x 16 x 256) -> pooled -> relu(@fc2+b2) -> @fc3+b3 -> log_softmax
// ---------------------------------------------------------------------------
__global__ __launch_bounds__(256) void sattfinal_k(
    const float* __restrict__ z2, const float* __restrict__ sw,
    const float* __restrict__ sb, const float* __restrict__ sv,
    const float* __restrict__ w2, const float* __restrict__ b2,
    const float* __restrict__ w3, const float* __restrict__ b3,
    float* __restrict__ out)
{
    const int b = blockIdx.x;
    const int tid = threadIdx.x;
    __shared__ float zs[16][256];
    for (int idx = tid; idx < 16 * 256; idx += 256) {
        int r = idx >> 8, c = idx & 255;
        zs[r][c] = z2[((long)b * 16 + r) * 256 + c];
    }
    __syncthreads();

    float acc[16] = {};
    for (int k = 0; k < 256; ++k) {
        float w = sw[k * 256 + tid];
        #pragma unroll
        for (int r = 0; r < 16; ++r) acc[r] += zs[r][k] * w;
    }
    const float sbv = sb[tid], svv = sv[tid];

    __shared__ float red[16][4];
    __shared__ float logit_s[16], alpha_s[16];
    const int warp = tid >> 6, lane = tid & 63;
    #pragma unroll
    for (int r = 0; r < 16; ++r) {
        float u = fmaxf(acc[r] + sbv, 0.f);
        float lv = u * svv;
        #pragma unroll
        for (int off = 32; off; off >>= 1) lv += __shfl_down(lv, off, 64);
        if (lane == 0) red[r][warp] = lv;
    }
    __syncthreads();
    if (tid < 16) logit_s[tid] = red[tid][0] + red[tid][1] + red[tid][2] + red[tid][3];
    __syncthreads();
    if (tid < 16) {
        float m = -INFINITY;
        #pragma unroll
        for (int i = 0; i < 16; ++i) m = fmaxf(m, logit_s[i]);
        float ssum = 0.f;
        #pragma unroll
        for (int i = 0; i < 16; ++i) ssum += expf(logit_s[i] - m);
        alpha_s[tid] = expf(logit_s[tid] - m) / ssum;
    }
    __syncthreads();
    float pacc = 0.f;
    #pragma unroll
    for (int r = 0; r < 16; ++r) pacc += alpha_s[r] * zs[r][tid];

    __shared__ float ps[256], z3s[128], z4s[10];
    ps[tid] = pacc;
    __syncthreads();
    if (tid < 128){
        float a2 = b2[tid];
        for (int k = 0; k < 256; ++k) a2 += ps[k] * w2[k * 128 + tid];
        z3s[tid] = fmaxf(a2, 0.f);
    }
    __syncthreads();
    if (tid < 10){
        float a3 = b3[tid];
        for (int k = 0; k < 128; ++k) a3 += z3s[k] * w3[k * 10 + tid];
        z4s[tid] = a3;
    }
    __syncthreads();
    if (tid < 10){
        float m = z4s[0];
        #pragma unroll
        for (int i = 1; i < 10; ++i) m = fmaxf(m, z4s[i]);
        float s = 0.f;
        #pragma unroll
        for (int i = 0; i < 10; ++i) s += expf(z4s[i] - m);
        out[b * 10 + tid] = z4s[tid] - m - logf(s);
    }
}

// ---------------------------------------------------------------------------
extern "C" void kernel_launch(void* const* d_in, const int* in_sizes, int n_in,
                              void* d_out, int out_size, void* d_ws, size_t ws_size,
                              hipStream_t stream)
{
    const int*   x      = (const int*)d_in[0];
    const float* adj    = (const float*)d_in[1];
    // d_in[2] = adj_s (unused), d_in[3]/d_in[4] = shape scalars
    const float* emb    = (const float*)d_in[5];
    const float* mp0_w1 = (const float*)d_in[6];
    const float* mp0_b1 = (const float*)d_in[7];
    const float* mp0_w2 = (const float*)d_in[8];
    const float* mp0_b2 = (const float*)d_in[9];
    const float* mp1_w1 = (const float*)d_in[10];
    const float* mp1_b1 = (const float*)d_in[11];
    const float* mp1_w2 = (const float*)d_in[12];
    const float* mp1_b2 = (const float*)d_in[13];
    const float* att0_w = (const float*)d_in[14];
    const float* att0_b = (const float*)d_in[15];
    const float* att0_v = (const float*)d_in[16];
    const float* att1_w = (const float*)d_in[17];
    const float* att1_b = (const float*)d_in[18];
    const float* att1_v = (const float*)d_in[19];
    const float* bn_g   = (const float*)d_in[20];
    const float* bn_b   = (const float*)d_in[21];
    const float* fc1_w  = (const float*)d_in[22];
    const float* fc1_b  = (const float*)d_in[23];
    const float* satt_w = (const float*)d_in[24];
    const float* satt_b = (const float*)d_in[25];
    const float* satt_v = (const float*)d_in[26];
    const float* fc2_w  = (const float*)d_in[27];
    const float* fc2_b  = (const float*)d_in[28];
    const float* fc3_w  = (const float*)d_in[29];
    const float* fc3_b  = (const float*)d_in[30];
    float* out = (float*)d_out;

    float* ws = (float*)d_ws;
    float* z2      = ws;                    // 2048*256 f32
    float* scale   = z2 + 2048L * 256;      // 1024
    float* shiftv  = scale + 1024;          // 1024
    float* biasp   = shiftv + 1024;         // 256
    u16*   wbase   = (u16*)(biasp + 256);
    u16* wb_w1a  = wbase;                   // 81920 u16 (K=320 tiled)
    u16* wb_w2a  = wb_w1a + 81920;          // 65536 each below
    u16* wb_awa  = wb_w2a + 65536;
    u16* wb_w1b  = wb_awa + 65536;
    u16* wb_w2b  = wb_w1b + 65536;
    u16* wb_awb  = wb_w2b + 65536;
    u16* adjb    = wb_awb + 65536;          // 2048*4096 u16 (16.8 MB)
    u16* zb      = adjb + 2048L*4096;       // 2048*1024 u16 (4.2 MB)
    u16* fc1blob = zb + 2048L*1024;         // 262144 u16
    u16* eprime  = fc1blob + 262144;        // 50048*256 u16 (25.6 MB)
    // total ws ~ 50 MB

    conv_all_k<<<dim3(1600), dim3(256), 0, stream>>>(
        mp0_w1, mp0_w2, att0_w, mp1_w1, mp1_w2, att1_w, wbase);
    adjconv_k<<<dim3(8192), dim3(256), 0, stream>>>(adj, adjb);
    eprime_k<<<dim3(1563), dim3(512), 0, stream>>>(emb, wb_w1a, eprime);

    mega_k<<<dim3(1024), dim3(512), 0, stream>>>(
        x, adjb, eprime,
        wb_w2a, wb_awa, wb_w1b, wb_w2b, wb_awb,
        mp0_b1, mp0_b2, att0_b, att0_v,
        mp1_b1, mp1_b2, att1_b, att1_v, zb);

    bnstats_k<<<dim3(256), dim3(256), 0, stream>>>(zb, bn_g, bn_b, scale, shiftv);
    fc1prep_k<<<dim3(1280), dim3(256), 0, stream>>>(fc1_w, scale, shiftv, fc1_b,
        fc1blob, biasp);
    fc1_mfma_k<<<dim3(2, 64), dim3(256), 0, stream>>>(zb, fc1blob, biasp, z2);
    sattfinal_k<<<dim3(128), dim3(256), 0, stream>>>(z2, satt_w, satt_b, satt_v,
        fc2_w, fc2_b, fc3_w, fc3_b, out);
}

// Round 18
// 287.593 us; speedup vs baseline: 1.2174x; 1.2174x over previous
//
#include <hip/hip_runtime.h>
#include <math.h>

// Dims: V=50000 F=300 H=256 P=128 C=10  B=128 S=16 N=64  G=2048 T=131072
// r18 = exact revert to r16's measured-best configuration (287.6us):
// r17's feature-split S3/S4 regressed (persistent lgt stayed live across
// K-loops -> more spill). r15 node-split passes are the empirical optimum.

typedef unsigned short u16;
typedef __attribute__((ext_vector_type(8))) short bf16x8;
typedef __attribute__((ext_vector_type(4))) float f32x4;

__device__ __forceinline__ float b2f(u16 v){ return __uint_as_float(((unsigned)v)<<16); }
__device__ __forceinline__ u16 f2b(float f){
    unsigned u = __float_as_uint(f);
    return (u16)((u + 0x7FFFu + ((u>>16)&1u)) >> 16);   // RNE
}
__device__ __forceinline__ ushort4 pack4(float a,float b,float c,float d){
    ushort4 o; o.x=f2b(a); o.y=f2b(b); o.z=f2b(c); o.w=f2b(d); return o;
}

// Per-graph LDS = 64 KB = two 32 KB regions that PING-PONG between phases.
__device__ __forceinline__ int srow_rb(int nd, int f){
    return (nd*512 + f*2) ^ ((nd&7)<<4);
}
__device__ __forceinline__ int scol_rb(int f, int nd){
    return (f*128 + nd*2) ^ ((f&7)<<4);
}
__device__ __forceinline__ int wfrag_off(int ni){
    return ((ni>>1)<<10) + ((ni&1)<<9);
}

// ---------------------------------------------------------------------------
// Megakernel (r15/r16 proven config): 1024 blocks x 512 threads; block = TWO
// graphs. Serial node-split half-passes (#pragma unroll 1) keep one acc[4][2]
// live. launch_bounds(512,1).
// ---------------------------------------------------------------------------
__global__ __launch_bounds__(512, 1) void mega_k(
    const int* __restrict__ x, const u16* __restrict__ adjb,
    const u16* __restrict__ eprime,
    const u16* __restrict__ wb_w2a, const u16* __restrict__ wb_awa,
    const u16* __restrict__ wb_w1b, const u16* __restrict__ wb_w2b,
    const u16* __restrict__ wb_awb,
    const float* __restrict__ b1a, const float* __restrict__ b2a,
    const float* __restrict__ aba, const float* __restrict__ ava,
    const float* __restrict__ b1b, const float* __restrict__ b2b,
    const float* __restrict__ abb, const float* __restrict__ avb,
    u16* __restrict__ zb)
{
    __shared__ __align__(16) char sm[131072];
    const int tid = threadIdx.x;
    const int w = tid>>6, l = tid&63, lgp = l>>4, ll = l&15;
    const int q = w>>2, w4 = w&3, slab = w4*64;
    const long g = (long)blockIdx.x*2 + q;
    char* smq = sm + q*65536;
    const f32x4 zero4 = {0.f,0.f,0.f,0.f};

    // ---------------- S1: gather E'[x] rows for BOTH graphs -> scol @ R1
    {
        const int r2 = tid >> 3;           // node 0..63
        const int fc = (tid & 7) * 32;     // 32-feature chunk
        #pragma unroll
        for (int q2=0; q2<2; ++q2){
            const u16* ep = eprime + (long)x[((long)blockIdx.x*2+q2)*64 + r2]*256 + fc;
            char* smr = sm + q2*65536 + 32768;
            uint4 qa = *(const uint4*)(ep);
            uint4 qb = *(const uint4*)(ep + 8);
            uint4 qc = *(const uint4*)(ep + 16);
            uint4 qd = *(const uint4*)(ep + 24);
            #pragma unroll
            for (int qi=0; qi<4; ++qi){
                uint4 v = (qi==0)?qa:(qi==1)?qb:(qi==2)?qc:qd;
                unsigned xw[4] = {v.x, v.y, v.z, v.w};
                #pragma unroll
                for (int wi=0; wi<4; ++wi){
                    unsigned u = xw[wi];
                    int f0 = fc + qi*8 + wi*2;
                    *(u16*)(smr + scol_rb(f0,   r2)) = (u16)(u & 0xffffu);
                    *(u16*)(smr + scol_rb(f0+1, r2)) = (u16)(u >> 16);
                }
            }
        }
        __syncthreads();
    }

    const u16* adjg = adjb + g*4096;

    // ========== layer loop ==========
    #pragma unroll 1
    for (int layer=0; layer<2; ++layer){
        const u16* wb_w2 = layer ? wb_w2b : wb_w2a;
        const u16* wb_aw = layer ? wb_awb : wb_awa;
        const float* b1  = layer ? b1b : b1a;
        const float* b2  = layer ? b2b : b2a;
        const float* ab  = layer ? abb : aba;
        const float* av  = layer ? avb : ava;
        const int zoff   = layer ? 512 : 0;
        const int pA = layer ? 0 : 32768;
        const int pB = layer ? 32768 : 0;

        // ---------- S2: T = relu(adj @ P + b1): scol@pA -> srow@pB
        #pragma unroll 1
        for (int nh=0; nh<2; ++nh){
            f32x4 acc[4][2];
            #pragma unroll
            for (int i=0;i<4;++i){ acc[i][0] = zero4; acc[i][1] = zero4; }
            #pragma unroll
            for (int t=0;t<2;++t){
                const int k0 = t*32 + lgp*8;
                bf16x8 a[4], b[2];
                #pragma unroll
                for (int mi=0;mi<4;++mi)
                    a[mi] = *(const bf16x8*)(smq + pA + scol_rb(slab + mi*16 + ll, k0));
                #pragma unroll
                for (int ni=0;ni<2;++ni)
                    b[ni] = *(const bf16x8*)(adjg + ((nh*2+ni)*16+ll)*64 + k0);
                #pragma unroll
                for (int mi=0;mi<4;++mi){
                    acc[mi][0] = __builtin_amdgcn_mfma_f32_16x16x32_bf16(a[mi], b[0], acc[mi][0],0,0,0);
                    acc[mi][1] = __builtin_amdgcn_mfma_f32_16x16x32_bf16(a[mi], b[1], acc[mi][1],0,0,0);
                }
            }
            #pragma unroll
            for (int mi=0;mi<4;++mi){
                int f0 = slab + mi*16 + lgp*4;
                float4 bi = *(const float4*)(b1 + f0);
                #pragma unroll
                for (int ni=0;ni<2;++ni){
                    int nd = (nh*2+ni)*16 + ll;
                    f32x4 v = acc[mi][ni];
                    *(ushort4*)(smq + pB + srow_rb(nd, f0)) = pack4(
                        fmaxf(v[0]+bi.x,0.f), fmaxf(v[1]+bi.y,0.f),
                        fmaxf(v[2]+bi.z,0.f), fmaxf(v[3]+bi.w,0.f));
                }
            }
        }
        __syncthreads();

        // ---------- S3: H = relu(T @ w2 + b2): srow@pB -> srow@pA
        #pragma unroll 1
        for (int nh=0; nh<2; ++nh){
            f32x4 acc[4][2];
            #pragma unroll
            for (int i=0;i<4;++i){ acc[i][0] = zero4; acc[i][1] = zero4; }
            const u16* chw = wb_w2 + ((w4*2)<<10) + ll*32 + lgp*8;
            #pragma unroll
            for (int t=0;t<8;++t){
                const u16* ct = chw + t*8192;
                const int k0 = t*32 + lgp*8;
                bf16x8 cw0 = *(const bf16x8*)(ct + wfrag_off(0));
                bf16x8 cw1 = *(const bf16x8*)(ct + wfrag_off(1));
                bf16x8 cw2 = *(const bf16x8*)(ct + wfrag_off(2));
                bf16x8 cw3 = *(const bf16x8*)(ct + wfrag_off(3));
                bf16x8 b[2];
                #pragma unroll
                for (int ni=0;ni<2;++ni)
                    b[ni] = *(const bf16x8*)(smq + pB + srow_rb((nh*2+ni)*16+ll, k0));
                #pragma unroll
                for (int ni=0;ni<2;++ni){
                    acc[0][ni] = __builtin_amdgcn_mfma_f32_16x16x32_bf16(cw0, b[ni], acc[0][ni],0,0,0);
                    acc[1][ni] = __builtin_amdgcn_mfma_f32_16x16x32_bf16(cw1, b[ni], acc[1][ni],0,0,0);
                    acc[2][ni] = __builtin_amdgcn_mfma_f32_16x16x32_bf16(cw2, b[ni], acc[2][ni],0,0,0);
                    acc[3][ni] = __builtin_amdgcn_mfma_f32_16x16x32_bf16(cw3, b[ni], acc[3][ni],0,0,0);
                }
            }
            #pragma unroll
            for (int mi=0;mi<4;++mi){
                int f0 = slab + mi*16 + lgp*4;
                float4 bi = *(const float4*)(b2 + f0);
                #pragma unroll
                for (int ni=0;ni<2;++ni){
                    int nd = (nh*2+ni)*16 + ll;
                    f32x4 v = acc[mi][ni];
                    *(ushort4*)(smq + pA + srow_rb(nd, f0)) = pack4(
                        fmaxf(v[0]+bi.x,0.f), fmaxf(v[1]+bi.y,0.f),
                        fmaxf(v[2]+bi.z,0.f), fmaxf(v[3]+bi.w,0.f));
                }
            }
        }
        __syncthreads();

        // ---------- S4: attention: H srow@pA, scratch@pB
        {
            float abv[4], avv[4];
            #pragma unroll
            for (int ni=0;ni<4;++ni){
                int c = slab + ni*16 + ll;
                abv[ni] = ab[c]; avv[ni] = av[c];
            }
            float* red = (float*)(smq + pB);
            #pragma unroll 1
            for (int mh=0; mh<2; ++mh){
                f32x4 acc[2][4];
                #pragma unroll
                for (int j=0;j<4;++j){ acc[0][j] = zero4; acc[1][j] = zero4; }
                const u16* chw = wb_aw + ((w4*2)<<10) + ll*32 + lgp*8;
                #pragma unroll
                for (int t=0;t<8;++t){
                    const u16* ct = chw + t*8192;
                    const int k0 = t*32 + lgp*8;
                    bf16x8 cw0 = *(const bf16x8*)(ct + wfrag_off(0));
                    bf16x8 cw1 = *(const bf16x8*)(ct + wfrag_off(1));
                    bf16x8 cw2 = *(const bf16x8*)(ct + wfrag_off(2));
                    bf16x8 cw3 = *(const bf16x8*)(ct + wfrag_off(3));
                    bf16x8 a[2];
                    #pragma unroll
                    for (int mi=0;mi<2;++mi)
                        a[mi] = *(const bf16x8*)(smq + pA + srow_rb((mh*2+mi)*16+ll, k0));
                    #pragma unroll
                    for (int mi=0;mi<2;++mi){
                        acc[mi][0] = __builtin_amdgcn_mfma_f32_16x16x32_bf16(a[mi], cw0, acc[mi][0],0,0,0);
                        acc[mi][1] = __builtin_amdgcn_mfma_f32_16x16x32_bf16(a[mi], cw1, acc[mi][1],0,0,0);
                        acc[mi][2] = __builtin_amdgcn_mfma_f32_16x16x32_bf16(a[mi], cw2, acc[mi][2],0,0,0);
                        acc[mi][3] = __builtin_amdgcn_mfma_f32_16x16x32_bf16(a[mi], cw3, acc[mi][3],0,0,0);
                    }
                }
                float lgt[2][4];
                #pragma unroll
                for (int mi=0;mi<2;++mi){
                    #pragma unroll
                    for (int r=0;r<4;++r) lgt[mi][r] = 0.f;
                }
                #pragma unroll
                for (int mi=0;mi<2;++mi){
                    #pragma unroll
                    for (int ni=0;ni<4;++ni){
                        f32x4 v = acc[mi][ni];
                        #pragma unroll
                        for (int r=0;r<4;++r) lgt[mi][r] += fmaxf(v[r]+abv[ni],0.f)*avv[ni];
                    }
                }
                #pragma unroll
                for (int mi=0;mi<2;++mi){
                    #pragma unroll
                    for (int r=0;r<4;++r){
                        float vv = lgt[mi][r];
                        vv += __shfl_xor(vv,1,64); vv += __shfl_xor(vv,2,64);
                        vv += __shfl_xor(vv,4,64); vv += __shfl_xor(vv,8,64);
                        lgt[mi][r] = vv;
                    }
                }
                if (ll == 0){
                    #pragma unroll
                    for (int mi=0;mi<2;++mi){
                        #pragma unroll
                        for (int r=0;r<4;++r){
                            int node = (mh*2+mi)*16 + lgp*4 + r;
                            red[w4*64 + node] = lgt[mi][r];
                        }
                    }
                }
            }
            __syncthreads();
            if (tid < 128){
                int qs = tid >> 6, t64 = tid & 63;
                const float* rq = (const float*)(sm + qs*65536 + pB);
                float lv = rq[t64] + rq[64+t64] + rq[128+t64] + rq[192+t64];
                float v = (t64 < 63) ? lv : -INFINITY;
                float m = v;
                #pragma unroll
                for (int off=32; off; off>>=1) m = fmaxf(m, __shfl_xor(m, off, 64));
                float e = (t64 < 63) ? expf(v - m) : 0.f;
                float s = e;
                #pragma unroll
                for (int off=32; off; off>>=1) s += __shfl_xor(s, off, 64);
                *(float*)(sm + qs*65536 + pB + 1024 + t64*4) = e / s;
            }
            __syncthreads();
            {
                int qs = tid >> 8, c = tid & 255;
                char* smr = sm + qs*65536;
                const float* alpha = (const float*)(smr + pB + 1024);
                float pool = 0.f;
                for (int r=0;r<63;++r)
                    pool += alpha[r]*b2f(*(const u16*)(smr + pA + srow_rb(r,c)));
                long zb0 = ((long)blockIdx.x*2 + qs)*1024 + zoff;
                zb[zb0 + c]       = f2b(pool);
                zb[zb0 + 256 + c] = *(const u16*)(smr + pA + srow_rb(63,c));
            }
            __syncthreads();
        }

        // ---------- S5 (layer 0 only): P1 = H @ w1b: srow@pA -> scol@pB
        if (layer == 0){
            #pragma unroll 1
            for (int nh=0; nh<2; ++nh){
                f32x4 acc[4][2];
                #pragma unroll
                for (int i=0;i<4;++i){ acc[i][0] = zero4; acc[i][1] = zero4; }
                const u16* chw = wb_w1b + ((w4*2)<<10) + ll*32 + lgp*8;
                #pragma unroll
                for (int t=0;t<8;++t){
                    const u16* ct = chw + t*8192;
                    const int k0 = t*32 + lgp*8;
                    bf16x8 cwA = *(const bf16x8*)(ct + wfrag_off(nh*2+0));
                    bf16x8 cwB = *(const bf16x8*)(ct + wfrag_off(nh*2+1));
                    bf16x8 a[4];
                    #pragma unroll
                    for (int mi=0;mi<4;++mi)
                        a[mi] = *(const bf16x8*)(smq + pA + srow_rb(mi*16+ll, k0));
                    #pragma unroll
                    for (int mi=0;mi<4;++mi){
                        acc[mi][0] = __builtin_amdgcn_mfma_f32_16x16x32_bf16(a[mi], cwA, acc[mi][0],0,0,0);
                        acc[mi][1] = __builtin_amdgcn_mfma_f32_16x16x32_bf16(a[mi], cwB, acc[mi][1],0,0,0);
                    }
                }
                #pragma unroll
                for (int mi=0;mi<4;++mi){
                    #pragma unroll
                    for (int ni=0;ni<2;++ni){
                        int fo = slab + (nh*2+ni)*16 + ll, nd0 = mi*16 + lgp*4;
                        f32x4 v = acc[mi][ni];
                        *(ushort4*)(smq + pB + scol_rb(fo,nd0)) = pack4(v[0],v[1],v[2],v[3]);
                    }
                }
            }
            __syncthreads();
        }
    }
}

// ---------------------------------------------------------------------------
// E' = emb @ w1a  (50000x300 @ 300x256 -> bf16 50000x256 row-major).
// 512-thread blocks covering all 256 cols (grid 1563) -> emb read once.
// ---------------------------------------------------------------------------
__global__ __launch_bounds__(512) void eprime_k(
    const float* __restrict__ emb, const u16* __restrict__ blob,
    u16* __restrict__ eprime)
{
    __shared__ __align__(16) char sm[4096];     // 2 x 2KB A-tile dbuf
    const int m0 = blockIdx.x * 32;
    const int tid = threadIdx.x;
    const int w = tid>>6, l = tid&63, lgp = l>>4, ll = l&15;
    const f32x4 zero4 = {0.f,0.f,0.f,0.f};

    const int r  = tid >> 4;          // row 0..31
    const int kf = (tid & 15) * 2;    // float-pair index within 32
    int rowg = m0 + r; if (rowg > 49999) rowg = 49999;
    const long arow = (long)rowg * 300;
    const int wbyte = (r*64 + kf*2) ^ ((r&7)<<4);

    float2 pv = (kf + 2 <= 300) ? *(const float2*)(emb + arow + kf)
                                : make_float2(0.f,0.f);
    const u16* chw = blob + (w<<10) + ll*32 + lgp*8;
    bf16x8 w0 = *(const bf16x8*)(chw);
    bf16x8 w1 = *(const bf16x8*)(chw + 512);

    f32x4 acc[2][2];
    acc[0][0]=zero4; acc[0][1]=zero4; acc[1][0]=zero4; acc[1][1]=zero4;

    #pragma unroll
    for (int t=0;t<10;++t){
        float2 cur = pv;
        bf16x8 cw0 = w0, cw1 = w1;
        if (t < 9){
            int kn = (t+1)*32 + kf;
            pv = (kn + 2 <= 300) ? *(const float2*)(emb + arow + kn)
                                 : make_float2(0.f,0.f);
            const u16* nx = chw + (t+1)*8192;
            w0 = *(const bf16x8*)(nx);
            w1 = *(const bf16x8*)(nx + 512);
        }
        ushort2 st; st.x = f2b(cur.x); st.y = f2b(cur.y);
        *(ushort2*)(sm + (t&1)*2048 + wbyte) = st;
        __syncthreads();
        const char* eb = sm + (t&1)*2048;
        bf16x8 a0, a1;
        {
            int row = ll;
            a0 = *(const bf16x8*)(eb + ((row*64 + lgp*16) ^ ((row&7)<<4)));
            row = 16 + ll;
            a1 = *(const bf16x8*)(eb + ((row*64 + lgp*16) ^ ((row&7)<<4)));
        }
        acc[0][0] = __builtin_amdgcn_mfma_f32_16x16x32_bf16(a0, cw0, acc[0][0],0,0,0);
        acc[0][1] = __builtin_amdgcn_mfma_f32_16x16x32_bf16(a0, cw1, acc[0][1],0,0,0);
        acc[1][0] = __builtin_amdgcn_mfma_f32_16x16x32_bf16(a1, cw0, acc[1][0],0,0,0);
        acc[1][1] = __builtin_amdgcn_mfma_f32_16x16x32_bf16(a1, cw1, acc[1][1],0,0,0);
        __syncthreads();
    }
    #pragma unroll
    for (int mi=0;mi<2;++mi){
        #pragma unroll
        for (int ni=0;ni<2;++ni){
            int col = w*32 + ni*16 + ll;
            f32x4 v = acc[mi][ni];
            #pragma unroll
            for (int rr=0;rr<4;++rr){
                int row = m0 + mi*16 + lgp*4 + rr;
                if (row < 50000) eprime[(long)row*256 + col] = f2b(v[rr]);
            }
        }
    }
}

// ---------------------------------------------------------------------------
// Weight pre-pass: 6 GEMM weights -> bf16 8-slab K-tiled blobs (zero-pad K).
// ---------------------------------------------------------------------------
__global__ __launch_bounds__(256) void conv_all_k(
    const float* __restrict__ w1a, const float* __restrict__ w2a,
    const float* __restrict__ awa, const float* __restrict__ w1b,
    const float* __restrict__ w2b, const float* __restrict__ awb,
    u16* __restrict__ dst_base)
{
    long idx = (long)blockIdx.x*256 + threadIdx.x;
    if (idx >= 81920L + 5L*65536L) return;
    const float* src; u16* dst; int Ksrc; long rem;
    if (idx < 81920L){ src = w1a; dst = dst_base; Ksrc = 300; rem = idx; }
    else {
        long j = (idx - 81920L) / 65536L, r2 = (idx - 81920L) % 65536L;
        src = (j==0)?w2a:(j==1)?awa:(j==2)?w1b:(j==3)?w2b:awb;
        dst = dst_base + 81920L + j*65536L; Ksrc = 256; rem = r2;
    }
    int k = (int)(rem >> 8), n = (int)(rem & 255);
    float v = (k < Ksrc) ? src[k*256 + n] : 0.f;
    int t = k>>5, kk = k&31;
    dst[((t*8 + (n>>5))<<10) + (n&31)*32 + kk] = f2b(v);
}

// adj f32 -> bf16, float4/ushort4 vectorized
__global__ __launch_bounds__(256) void adjconv_k(
    const float* __restrict__ adj, u16* __restrict__ adjb)
{
    long i = ((long)blockIdx.x*256 + threadIdx.x) * 4;
    if (i >= 2048L*4096L) return;
    float4 v = *(const float4*)(adj + i);
    *(ushort4*)(adjb + i) = pack4(v.x, v.y, v.z, v.w);
}

// ---------------------------------------------------------------------------
// BatchNorm stats over rows of zb (2048 x 1024 bf16): scale/shift per column.
// ---------------------------------------------------------------------------
__global__ __launch_bounds__(256) void bnstats_k(
    const u16* __restrict__ zb, const float* __restrict__ gamma,
    const float* __restrict__ beta,
    float* __restrict__ scale, float* __restrict__ shift)
{
    const int tid = threadIdx.x;
    const int cl = tid & 3, ph = tid >> 2;
    const int c = blockIdx.x * 4 + cl;
    double s = 0.0, s2 = 0.0;
    #pragma unroll 8
    for (int r = ph; r < 2048; r += 64) {
        float v = b2f(zb[(long)r * 1024 + c]);
        s += v; s2 += (double)v * v;
    }
    __shared__ double ss[256], ss2[256];
    ss[tid] = s; ss2[tid] = s2;
    __syncthreads();
    for (int off = 128; off >= 4; off >>= 1){
        if (tid < off){ ss[tid] += ss[tid+off]; ss2[tid] += ss2[tid+off]; }
        __syncthreads();
    }
    if (tid < 4){
        int cc = blockIdx.x * 4 + tid;
        double mu = ss[tid] / 2048.0;
        double var = ss2[tid] / 2048.0 - mu * mu;
        float inv = (float)(1.0 / sqrt(var + 1e-5));
        float sc = gamma[cc] * inv;
        scale[cc] = sc;
        shift[cc] = beta[cc] - (float)mu * sc;
    }
}

// ---------------------------------------------------------------------------
// fc1 prep (merged): blocks [0,1024) build the bn-scaled bf16 weight blob;
// blocks [1024,1280) build the fused bias.
// ---------------------------------------------------------------------------
__global__ __launch_bounds__(256) void fc1prep_k(
    const float* __restrict__ fw, const float* __restrict__ scale,
    const float* __restrict__ shift, const float* __restrict__ fb,
    u16* __restrict__ dst, float* __restrict__ biasp)
{
    if (blockIdx.x < 1024){
        int lin = blockIdx.x*256 + threadIdx.x;           // 262144 total
        int c = lin >> 10, t = c >> 3, s = c & 7;
        int nl = (lin >> 5) & 31, kk = lin & 31;
        int n = s*32 + nl, k = t*32 + kk;
        dst[lin] = f2b(fw[k*256 + n] * scale[k]);
    } else {
        const int n = blockIdx.x - 1024, tid = threadIdx.x;
        float p = 0.f;
        #pragma unroll
        for (int i=0;i<4;++i){
            int k = tid + i*256;
            p += shift[k] * fw[k*256 + n];
        }
        __shared__ float red[256];
        red[tid] = p;
        __syncthreads();
        for (int off=128; off; off>>=1){
            if (tid < off) red[tid] += red[tid+off];
            __syncthreads();
        }
        if (tid == 0) biasp[n] = fb[n] + red[0];
    }
}

// ---------------------------------------------------------------------------
// fc1 MFMA: z2 = relu(zb @ W' + biasp)  (2048x1024 @ 1024x256, bn absorbed)
// ---------------------------------------------------------------------------
__global__ __launch_bounds__(256) void fc1_mfma_k(
    const u16* __restrict__ zb, const u16* __restrict__ blob,
    const float* __restrict__ biasp, float* __restrict__ z2)
{
    __shared__ __align__(16) char sm[4096];     // 2 x 2KB A-tile dbuf
    const int h = blockIdx.x, m0 = blockIdx.y * 32;
    const int tid = threadIdx.x;
    const int w = tid>>6, l = tid&63, lgp = l>>4, ll = l&15;
    const f32x4 zero4 = {0.f,0.f,0.f,0.f};
    const int slab = h*4 + w;

    const int r  = tid >> 3;          // row 0..31
    const int kc = (tid & 7) * 4;     // k-chunk within 32
    const long arow = (long)(m0 + r) * 1024;
    const int wbyte = (r*64 + (tid&7)*8) ^ ((r&7)<<4);

    ushort4 pv = *(const ushort4*)(zb + arow + kc);
    const u16* chw = blob + (slab<<10) + ll*32 + lgp*8;
    bf16x8 w0 = *(const bf16x8*)(chw);
    bf16x8 w1 = *(const bf16x8*)(chw + 512);

    f32x4 acc[2][2];
    acc[0][0]=zero4; acc[0][1]=zero4; acc[1][0]=zero4; acc[1][1]=zero4;

    #pragma unroll 4
    for (int t=0;t<32;++t){
        ushort4 cur = pv;
        bf16x8 cw0 = w0, cw1 = w1;
        if (t < 31){
            pv = *(const ushort4*)(zb + arow + (t+1)*32 + kc);
            const u16* nx = chw + (t+1)*8192;
            w0 = *(const bf16x8*)(nx);
            w1 = *(const bf16x8*)(nx + 512);
        }
        *(ushort4*)(sm + (t&1)*2048 + wbyte) = cur;
        __syncthreads();
        const char* eb = sm + (t&1)*2048;
        bf16x8 a0, a1;
        {
            int row = ll;
            a0 = *(const bf16x8*)(eb + ((row*64 + lgp*16) ^ ((row&7)<<4)));
            row = 16 + ll;
            a1 = *(const bf16x8*)(eb + ((row*64 + lgp*16) ^ ((row&7)<<4)));
        }
        acc[0][0] = __builtin_amdgcn_mfma_f32_16x16x32_bf16(a0, cw0, acc[0][0],0,0,0);
        acc[0][1] = __builtin_amdgcn_mfma_f32_16x16x32_bf16(a0, cw1, acc[0][1],0,0,0);
        acc[1][0] = __builtin_amdgcn_mfma_f32_16x16x32_bf16(a1, cw0, acc[1][0],0,0,0);
        acc[1][1] = __builtin_amdgcn_mfma_f32_16x16x32_bf16(a1, cw1, acc[1][1],0,0,0);
        __syncthreads();
    }
    #pragma unroll
    for (int mi=0;mi<2;++mi){
        #pragma unroll
        for (int ni=0;ni<2;++ni){
            int col = h*128 + w*32 + ni*16 + ll;
            float bv = biasp[col];
            f32x4 v = acc[mi][ni];
            #pragma unroll
            for (int rr=0;rr<4;++rr){
                int row = m0 + mi*16 + lgp*4 + rr;
                z2[(long)row*256 + col] = fmaxf(v[rr] + bv, 0.f);
            }
        }
    }
}

// ---------------------------------------------------------------------------
// Segment attention + final head fused:
// z2 (128 x 16 x 256) -> pooled -> relu(@fc2+b2) -> @fc3+b3 -> log_softmax
// ---------------------------------------------------------------------------
__global__ __launch_bounds__(256) void sattfinal_k(
    const float* __restrict__ z2, const float* __restrict__ sw,
    const float* __restrict__ sb, const float* __restrict__ sv,
    const float* __restrict__ w2, const float* __restrict__ b2,
    const float* __restrict__ w3, const float* __restrict__ b3,
    float* __restrict__ out)
{
    const int b = blockIdx.x;
    const int tid = threadIdx.x;
    __shared__ float zs[16][256];
    for (int idx = tid; idx < 16 * 256; idx += 256) {
        int r = idx >> 8, c = idx & 255;
        zs[r][c] = z2[((long)b * 16 + r) * 256 + c];
    }
    __syncthreads();

    float acc[16] = {};
    for (int k = 0; k < 256; ++k) {
        float w = sw[k * 256 + tid];
        #pragma unroll
        for (int r = 0; r < 16; ++r) acc[r] += zs[r][k] * w;
    }
    const float sbv = sb[tid], svv = sv[tid];

    __shared__ float red[16][4];
    __shared__ float logit_s[16], alpha_s[16];
    const int warp = tid >> 6, lane = tid & 63;
    #pragma unroll
    for (int r = 0; r < 16; ++r) {
        float u = fmaxf(acc[r] + sbv, 0.f);
        float lv = u * svv;
        #pragma unroll
        for (int off = 32; off; off >>= 1) lv += __shfl_down(lv, off, 64);
        if (lane == 0) red[r][warp] = lv;
    }
    __syncthreads();
    if (tid < 16) logit_s[tid] = red[tid][0] + red[tid][1] + red[tid][2] + red[tid][3];
    __syncthreads();
    if (tid < 16) {
        float m = -INFINITY;
        #pragma unroll
        for (int i = 0; i < 16; ++i) m = fmaxf(m, logit_s[i]);
        float ssum = 0.f;
        #pragma unroll
        for (int i = 0; i < 16; ++i) ssum += expf(logit_s[i] - m);
        alpha_s[tid] = expf(logit_s[tid] - m) / ssum;
    }
    __syncthreads();
    float pacc = 0.f;
    #pragma unroll
    for (int r = 0; r < 16; ++r) pacc += alpha_s[r] * zs[r][tid];

    __shared__ float ps[256], z3s[128], z4s[10];
    ps[tid] = pacc;
    __syncthreads();
    if (tid < 128){
        float a2 = b2[tid];
        for (int k = 0; k < 256; ++k) a2 += ps[k] * w2[k * 128 + tid];
        z3s[tid] = fmaxf(a2, 0.f);
    }
    __syncthreads();
    if (tid < 10){
        float a3 = b3[tid];
        for (int k = 0; k < 128; ++k) a3 += z3s[k] * w3[k * 10 + tid];
        z4s[tid] = a3;
    }
    __syncthreads();
    if (tid < 10){
        float m = z4s[0];
        #pragma unroll
        for (int i = 1; i < 10; ++i) m = fmaxf(m, z4s[i]);
        float s = 0.f;
        #pragma unroll
        for (int i = 0; i < 10; ++i) s += expf(z4s[i] - m);
        out[b * 10 + tid] = z4s[tid] - m - logf(s);
    }
}

// ---------------------------------------------------------------------------
extern "C" void kernel_launch(void* const* d_in, const int* in_sizes, int n_in,
                              void* d_out, int out_size, void* d_ws, size_t ws_size,
                              hipStream_t stream)
{
    const int*   x      = (const int*)d_in[0];
    const float* adj    = (const float*)d_in[1];
    // d_in[2] = adj_s (unused), d_in[3]/d_in[4] = shape scalars
    const float* emb    = (const float*)d_in[5];
    const float* mp0_w1 = (const float*)d_in[6];
    const float* mp0_b1 = (const float*)d_in[7];
    const float* mp0_w2 = (const float*)d_in[8];
    const float* mp0_b2 = (const float*)d_in[9];
    const float* mp1_w1 = (const float*)d_in[10];
    const float* mp1_b1 = (const float*)d_in[11];
    const float* mp1_w2 = (const float*)d_in[12];
    const float* mp1_b2 = (const float*)d_in[13];
    const float* att0_w = (const float*)d_in[14];
    const float* att0_b = (const float*)d_in[15];
    const float* att0_v = (const float*)d_in[16];
    const float* att1_w = (const float*)d_in[17];
    const float* att1_b = (const float*)d_in[18];
    const float* att1_v = (const float*)d_in[19];
    const float* bn_g   = (const float*)d_in[20];
    const float* bn_b   = (const float*)d_in[21];
    const float* fc1_w  = (const float*)d_in[22];
    const float* fc1_b  = (const float*)d_in[23];
    const float* satt_w = (const float*)d_in[24];
    const float* satt_b = (const float*)d_in[25];
    const float* satt_v = (const float*)d_in[26];
    const float* fc2_w  = (const float*)d_in[27];
    const float* fc2_b  = (const float*)d_in[28];
    const float* fc3_w  = (const float*)d_in[29];
    const float* fc3_b  = (const float*)d_in[30];
    float* out = (float*)d_out;

    float* ws = (float*)d_ws;
    float* z2      = ws;                    // 2048*256 f32
    float* scale   = z2 + 2048L * 256;      // 1024
    float* shiftv  = scale + 1024;          // 1024
    float* biasp   = shiftv + 1024;         // 256
    u16*   wbase   = (u16*)(biasp + 256);
    u16* wb_w1a  = wbase;                   // 81920 u16 (K=320 tiled)
    u16* wb_w2a  = wb_w1a + 81920;          // 65536 each below
    u16* wb_awa  = wb_w2a + 65536;
    u16* wb_w1b  = wb_awa + 65536;
    u16* wb_w2b  = wb_w1b + 65536;
    u16* wb_awb  = wb_w2b + 65536;
    u16* adjb    = wb_awb + 65536;          // 2048*4096 u16 (16.8 MB)
    u16* zb      = adjb + 2048L*4096;       // 2048*1024 u16 (4.2 MB)
    u16* fc1blob = zb + 2048L*1024;         // 262144 u16
    u16* eprime  = fc1blob + 262144;        // 50048*256 u16 (25.6 MB)
    // total ws ~ 50 MB

    conv_all_k<<<dim3(1600), dim3(256), 0, stream>>>(
        mp0_w1, mp0_w2, att0_w, mp1_w1, mp1_w2, att1_w, wbase);
    adjconv_k<<<dim3(8192), dim3(256), 0, stream>>>(adj, adjb);
    eprime_k<<<dim3(1563), dim3(512), 0, stream>>>(emb, wb_w1a, eprime);

    mega_k<<<dim3(1024), dim3(512), 0, stream>>>(
        x, adjb, eprime,
        wb_w2a, wb_awa, wb_w1b, wb_w2b, wb_awb,
        mp0_b1, mp0_b2, att0_b, att0_v,
        mp1_b1, mp1_b2, att1_b, att1_v, zb);

    bnstats_k<<<dim3(256), dim3(256), 0, stream>>>(zb, bn_g, bn_b, scale, shiftv);
    fc1prep_k<<<dim3(1280), dim3(256), 0, stream>>>(fc1_w, scale, shiftv, fc1_b,
        fc1blob, biasp);
    fc1_mfma_k<<<dim3(2, 64), dim3(256), 0, stream>>>(zb, fc1blob, biasp, z2);
    sattfinal_k<<<dim3(128), dim3(256), 0, stream>>>(z2, satt_w, satt_b, satt_v,
        fc2_w, fc2_b, fc3_w, fc3_b, out);
}

// Round 19
// 284.529 us; speedup vs baseline: 1.2305x; 1.0108x over previous
//
#include <hip/hip_runtime.h>
#include <math.h>

// Dims: V=50000 F=300 H=256 P=128 C=10  B=128 S=16 N=64  G=2048 T=131072
// r19 = r18 (proven 287.6us) + tail-only tweaks:
//  - fc1_mfma regrid 128 -> 256 blocks (full CU coverage)
//  - conv_all + adjconv merged into one prep_k launch
// mega_k is byte-identical to r18 (frozen at its empirical optimum).

typedef unsigned short u16;
typedef __attribute__((ext_vector_type(8))) short bf16x8;
typedef __attribute__((ext_vector_type(4))) float f32x4;

__device__ __forceinline__ float b2f(u16 v){ return __uint_as_float(((unsigned)v)<<16); }
__device__ __forceinline__ u16 f2b(float f){
    unsigned u = __float_as_uint(f);
    return (u16)((u + 0x7FFFu + ((u>>16)&1u)) >> 16);   // RNE
}
__device__ __forceinline__ ushort4 pack4(float a,float b,float c,float d){
    ushort4 o; o.x=f2b(a); o.y=f2b(b); o.z=f2b(c); o.w=f2b(d); return o;
}

// Per-graph LDS = 64 KB = two 32 KB regions that PING-PONG between phases.
__device__ __forceinline__ int srow_rb(int nd, int f){
    return (nd*512 + f*2) ^ ((nd&7)<<4);
}
__device__ __forceinline__ int scol_rb(int f, int nd){
    return (f*128 + nd*2) ^ ((f&7)<<4);
}
__device__ __forceinline__ int wfrag_off(int ni){
    return ((ni>>1)<<10) + ((ni&1)<<9);
}

// ---------------------------------------------------------------------------
// Megakernel (r15/r16/r18 proven config — FROZEN): 1024 blocks x 512 threads;
// block = TWO graphs. Serial node-split half-passes (#pragma unroll 1).
// ---------------------------------------------------------------------------
__global__ __launch_bounds__(512, 1) void mega_k(
    const int* __restrict__ x, const u16* __restrict__ adjb,
    const u16* __restrict__ eprime,
    const u16* __restrict__ wb_w2a, const u16* __restrict__ wb_awa,
    const u16* __restrict__ wb_w1b, const u16* __restrict__ wb_w2b,
    const u16* __restrict__ wb_awb,
    const float* __restrict__ b1a, const float* __restrict__ b2a,
    const float* __restrict__ aba, const float* __restrict__ ava,
    const float* __restrict__ b1b, const float* __restrict__ b2b,
    const float* __restrict__ abb, const float* __restrict__ avb,
    u16* __restrict__ zb)
{
    __shared__ __align__(16) char sm[131072];
    const int tid = threadIdx.x;
    const int w = tid>>6, l = tid&63, lgp = l>>4, ll = l&15;
    const int q = w>>2, w4 = w&3, slab = w4*64;
    const long g = (long)blockIdx.x*2 + q;
    char* smq = sm + q*65536;
    const f32x4 zero4 = {0.f,0.f,0.f,0.f};

    // ---------------- S1: gather E'[x] rows for BOTH graphs -> scol @ R1
    {
        const int r2 = tid >> 3;           // node 0..63
        const int fc = (tid & 7) * 32;     // 32-feature chunk
        #pragma unroll
        for (int q2=0; q2<2; ++q2){
            const u16* ep = eprime + (long)x[((long)blockIdx.x*2+q2)*64 + r2]*256 + fc;
            char* smr = sm + q2*65536 + 32768;
            uint4 qa = *(const uint4*)(ep);
            uint4 qb = *(const uint4*)(ep + 8);
            uint4 qc = *(const uint4*)(ep + 16);
            uint4 qd = *(const uint4*)(ep + 24);
            #pragma unroll
            for (int qi=0; qi<4; ++qi){
                uint4 v = (qi==0)?qa:(qi==1)?qb:(qi==2)?qc:qd;
                unsigned xw[4] = {v.x, v.y, v.z, v.w};
                #pragma unroll
                for (int wi=0; wi<4; ++wi){
                    unsigned u = xw[wi];
                    int f0 = fc + qi*8 + wi*2;
                    *(u16*)(smr + scol_rb(f0,   r2)) = (u16)(u & 0xffffu);
                    *(u16*)(smr + scol_rb(f0+1, r2)) = (u16)(u >> 16);
                }
            }
        }
        __syncthreads();
    }

    const u16* adjg = adjb + g*4096;

    // ========== layer loop ==========
    #pragma unroll 1
    for (int layer=0; layer<2; ++layer){
        const u16* wb_w2 = layer ? wb_w2b : wb_w2a;
        const u16* wb_aw = layer ? wb_awb : wb_awa;
        const float* b1  = layer ? b1b : b1a;
        const float* b2  = layer ? b2b : b2a;
        const float* ab  = layer ? abb : aba;
        const float* av  = layer ? avb : ava;
        const int zoff   = layer ? 512 : 0;
        const int pA = layer ? 0 : 32768;
        const int pB = layer ? 32768 : 0;

        // ---------- S2: T = relu(adj @ P + b1): scol@pA -> srow@pB
        #pragma unroll 1
        for (int nh=0; nh<2; ++nh){
            f32x4 acc[4][2];
            #pragma unroll
            for (int i=0;i<4;++i){ acc[i][0] = zero4; acc[i][1] = zero4; }
            #pragma unroll
            for (int t=0;t<2;++t){
                const int k0 = t*32 + lgp*8;
                bf16x8 a[4], b[2];
                #pragma unroll
                for (int mi=0;mi<4;++mi)
                    a[mi] = *(const bf16x8*)(smq + pA + scol_rb(slab + mi*16 + ll, k0));
                #pragma unroll
                for (int ni=0;ni<2;++ni)
                    b[ni] = *(const bf16x8*)(adjg + ((nh*2+ni)*16+ll)*64 + k0);
                #pragma unroll
                for (int mi=0;mi<4;++mi){
                    acc[mi][0] = __builtin_amdgcn_mfma_f32_16x16x32_bf16(a[mi], b[0], acc[mi][0],0,0,0);
                    acc[mi][1] = __builtin_amdgcn_mfma_f32_16x16x32_bf16(a[mi], b[1], acc[mi][1],0,0,0);
                }
            }
            #pragma unroll
            for (int mi=0;mi<4;++mi){
                int f0 = slab + mi*16 + lgp*4;
                float4 bi = *(const float4*)(b1 + f0);
                #pragma unroll
                for (int ni=0;ni<2;++ni){
                    int nd = (nh*2+ni)*16 + ll;
                    f32x4 v = acc[mi][ni];
                    *(ushort4*)(smq + pB + srow_rb(nd, f0)) = pack4(
                        fmaxf(v[0]+bi.x,0.f), fmaxf(v[1]+bi.y,0.f),
                        fmaxf(v[2]+bi.z,0.f), fmaxf(v[3]+bi.w,0.f));
                }
            }
        }
        __syncthreads();

        // ---------- S3: H = relu(T @ w2 + b2): srow@pB -> srow@pA
        #pragma unroll 1
        for (int nh=0; nh<2; ++nh){
            f32x4 acc[4][2];
            #pragma unroll
            for (int i=0;i<4;++i){ acc[i][0] = zero4; acc[i][1] = zero4; }
            const u16* chw = wb_w2 + ((w4*2)<<10) + ll*32 + lgp*8;
            #pragma unroll
            for (int t=0;t<8;++t){
                const u16* ct = chw + t*8192;
                const int k0 = t*32 + lgp*8;
                bf16x8 cw0 = *(const bf16x8*)(ct + wfrag_off(0));
                bf16x8 cw1 = *(const bf16x8*)(ct + wfrag_off(1));
                bf16x8 cw2 = *(const bf16x8*)(ct + wfrag_off(2));
                bf16x8 cw3 = *(const bf16x8*)(ct + wfrag_off(3));
                bf16x8 b[2];
                #pragma unroll
                for (int ni=0;ni<2;++ni)
                    b[ni] = *(const bf16x8*)(smq + pB + srow_rb((nh*2+ni)*16+ll, k0));
                #pragma unroll
                for (int ni=0;ni<2;++ni){
                    acc[0][ni] = __builtin_amdgcn_mfma_f32_16x16x32_bf16(cw0, b[ni], acc[0][ni],0,0,0);
                    acc[1][ni] = __builtin_amdgcn_mfma_f32_16x16x32_bf16(cw1, b[ni], acc[1][ni],0,0,0);
                    acc[2][ni] = __builtin_amdgcn_mfma_f32_16x16x32_bf16(cw2, b[ni], acc[2][ni],0,0,0);
                    acc[3][ni] = __builtin_amdgcn_mfma_f32_16x16x32_bf16(cw3, b[ni], acc[3][ni],0,0,0);
                }
            }
            #pragma unroll
            for (int mi=0;mi<4;++mi){
                int f0 = slab + mi*16 + lgp*4;
                float4 bi = *(const float4*)(b2 + f0);
                #pragma unroll
                for (int ni=0;ni<2;++ni){
                    int nd = (nh*2+ni)*16 + ll;
                    f32x4 v = acc[mi][ni];
                    *(ushort4*)(smq + pA + srow_rb(nd, f0)) = pack4(
                        fmaxf(v[0]+bi.x,0.f), fmaxf(v[1]+bi.y,0.f),
                        fmaxf(v[2]+bi.z,0.f), fmaxf(v[3]+bi.w,0.f));
                }
            }
        }
        __syncthreads();

        // ---------- S4: attention: H srow@pA, scratch@pB
        {
            float abv[4], avv[4];
            #pragma unroll
            for (int ni=0;ni<4;++ni){
                int c = slab + ni*16 + ll;
                abv[ni] = ab[c]; avv[ni] = av[c];
            }
            float* red = (float*)(smq + pB);
            #pragma unroll 1
            for (int mh=0; mh<2; ++mh){
                f32x4 acc[2][4];
                #pragma unroll
                for (int j=0;j<4;++j){ acc[0][j] = zero4; acc[1][j] = zero4; }
                const u16* chw = wb_aw + ((w4*2)<<10) + ll*32 + lgp*8;
                #pragma unroll
                for (int t=0;t<8;++t){
                    const u16* ct = chw + t*8192;
                    const int k0 = t*32 + lgp*8;
                    bf16x8 cw0 = *(const bf16x8*)(ct + wfrag_off(0));
                    bf16x8 cw1 = *(const bf16x8*)(ct + wfrag_off(1));
                    bf16x8 cw2 = *(const bf16x8*)(ct + wfrag_off(2));
                    bf16x8 cw3 = *(const bf16x8*)(ct + wfrag_off(3));
                    bf16x8 a[2];
                    #pragma unroll
                    for (int mi=0;mi<2;++mi)
                        a[mi] = *(const bf16x8*)(smq + pA + srow_rb((mh*2+mi)*16+ll, k0));
                    #pragma unroll
                    for (int mi=0;mi<2;++mi){
                        acc[mi][0] = __builtin_amdgcn_mfma_f32_16x16x32_bf16(a[mi], cw0, acc[mi][0],0,0,0);
                        acc[mi][1] = __builtin_amdgcn_mfma_f32_16x16x32_bf16(a[mi], cw1, acc[mi][1],0,0,0);
                        acc[mi][2] = __builtin_amdgcn_mfma_f32_16x16x32_bf16(a[mi], cw2, acc[mi][2],0,0,0);
                        acc[mi][3] = __builtin_amdgcn_mfma_f32_16x16x32_bf16(a[mi], cw3, acc[mi][3],0,0,0);
                    }
                }
                float lgt[2][4];
                #pragma unroll
                for (int mi=0;mi<2;++mi){
                    #pragma unroll
                    for (int r=0;r<4;++r) lgt[mi][r] = 0.f;
                }
                #pragma unroll
                for (int mi=0;mi<2;++mi){
                    #pragma unroll
                    for (int ni=0;ni<4;++ni){
                        f32x4 v = acc[mi][ni];
                        #pragma unroll
                        for (int r=0;r<4;++r) lgt[mi][r] += fmaxf(v[r]+abv[ni],0.f)*avv[ni];
                    }
                }
                #pragma unroll
                for (int mi=0;mi<2;++mi){
                    #pragma unroll
                    for (int r=0;r<4;++r){
                        float vv = lgt[mi][r];
                        vv += __shfl_xor(vv,1,64); vv += __shfl_xor(vv,2,64);
                        vv += __shfl_xor(vv,4,64); vv += __shfl_xor(vv,8,64);
                        lgt[mi][r] = vv;
                    }
                }
                if (ll == 0){
                    #pragma unroll
                    for (int mi=0;mi<2;++mi){
                        #pragma unroll
                        for (int r=0;r<4;++r){
                            int node = (mh*2+mi)*16 + lgp*4 + r;
                            red[w4*64 + node] = lgt[mi][r];
                        }
                    }
                }
            }
            __syncthreads();
            if (tid < 128){
                int qs = tid >> 6, t64 = tid & 63;
                const float* rq = (const float*)(sm + qs*65536 + pB);
                float lv = rq[t64] + rq[64+t64] + rq[128+t64] + rq[192+t64];
                float v = (t64 < 63) ? lv : -INFINITY;
                float m = v;
                #pragma unroll
                for (int off=32; off; off>>=1) m = fmaxf(m, __shfl_xor(m, off, 64));
                float e = (t64 < 63) ? expf(v - m) : 0.f;
                float s = e;
                #pragma unroll
                for (int off=32; off; off>>=1) s += __shfl_xor(s, off, 64);
                *(float*)(sm + qs*65536 + pB + 1024 + t64*4) = e / s;
            }
            __syncthreads();
            {
                int qs = tid >> 8, c = tid & 255;
                char* smr = sm + qs*65536;
                const float* alpha = (const float*)(smr + pB + 1024);
                float pool = 0.f;
                for (int r=0;r<63;++r)
                    pool += alpha[r]*b2f(*(const u16*)(smr + pA + srow_rb(r,c)));
                long zb0 = ((long)blockIdx.x*2 + qs)*1024 + zoff;
                zb[zb0 + c]       = f2b(pool);
                zb[zb0 + 256 + c] = *(const u16*)(smr + pA + srow_rb(63,c));
            }
            __syncthreads();
        }

        // ---------- S5 (layer 0 only): P1 = H @ w1b: srow@pA -> scol@pB
        if (layer == 0){
            #pragma unroll 1
            for (int nh=0; nh<2; ++nh){
                f32x4 acc[4][2];
                #pragma unroll
                for (int i=0;i<4;++i){ acc[i][0] = zero4; acc[i][1] = zero4; }
                const u16* chw = wb_w1b + ((w4*2)<<10) + ll*32 + lgp*8;
                #pragma unroll
                for (int t=0;t<8;++t){
                    const u16* ct = chw + t*8192;
                    const int k0 = t*32 + lgp*8;
                    bf16x8 cwA = *(const bf16x8*)(ct + wfrag_off(nh*2+0));
                    bf16x8 cwB = *(const bf16x8*)(ct + wfrag_off(nh*2+1));
                    bf16x8 a[4];
                    #pragma unroll
                    for (int mi=0;mi<4;++mi)
                        a[mi] = *(const bf16x8*)(smq + pA + srow_rb(mi*16+ll, k0));
                    #pragma unroll
                    for (int mi=0;mi<4;++mi){
                        acc[mi][0] = __builtin_amdgcn_mfma_f32_16x16x32_bf16(a[mi], cwA, acc[mi][0],0,0,0);
                        acc[mi][1] = __builtin_amdgcn_mfma_f32_16x16x32_bf16(a[mi], cwB, acc[mi][1],0,0,0);
                    }
                }
                #pragma unroll
                for (int mi=0;mi<4;++mi){
                    #pragma unroll
                    for (int ni=0;ni<2;++ni){
                        int fo = slab + (nh*2+ni)*16 + ll, nd0 = mi*16 + lgp*4;
                        f32x4 v = acc[mi][ni];
                        *(ushort4*)(smq + pB + scol_rb(fo,nd0)) = pack4(v[0],v[1],v[2],v[3]);
                    }
                }
            }
            __syncthreads();
        }
    }
}

// ---------------------------------------------------------------------------
// E' = emb @ w1a  (50000x300 @ 300x256 -> bf16 50000x256 row-major).
// 512-thread blocks covering all 256 cols (grid 1563) -> emb read once.
// ---------------------------------------------------------------------------
__global__ __launch_bounds__(512) void eprime_k(
    const float* __restrict__ emb, const u16* __restrict__ blob,
    u16* __restrict__ eprime)
{
    __shared__ __align__(16) char sm[4096];     // 2 x 2KB A-tile dbuf
    const int m0 = blockIdx.x * 32;
    const int tid = threadIdx.x;
    const int w = tid>>6, l = tid&63, lgp = l>>4, ll = l&15;
    const f32x4 zero4 = {0.f,0.f,0.f,0.f};

    const int r  = tid >> 4;          // row 0..31
    const int kf = (tid & 15) * 2;    // float-pair index within 32
    int rowg = m0 + r; if (rowg > 49999) rowg = 49999;
    const long arow = (long)rowg * 300;
    const int wbyte = (r*64 + kf*2) ^ ((r&7)<<4);

    float2 pv = (kf + 2 <= 300) ? *(const float2*)(emb + arow + kf)
                                : make_float2(0.f,0.f);
    const u16* chw = blob + (w<<10) + ll*32 + lgp*8;
    bf16x8 w0 = *(const bf16x8*)(chw);
    bf16x8 w1 = *(const bf16x8*)(chw + 512);

    f32x4 acc[2][2];
    acc[0][0]=zero4; acc[0][1]=zero4; acc[1][0]=zero4; acc[1][1]=zero4;

    #pragma unroll
    for (int t=0;t<10;++t){
        float2 cur = pv;
        bf16x8 cw0 = w0, cw1 = w1;
        if (t < 9){
            int kn = (t+1)*32 + kf;
            pv = (kn + 2 <= 300) ? *(const float2*)(emb + arow + kn)
                                 : make_float2(0.f,0.f);
            const u16* nx = chw + (t+1)*8192;
            w0 = *(const bf16x8*)(nx);
            w1 = *(const bf16x8*)(nx + 512);
        }
        ushort2 st; st.x = f2b(cur.x); st.y = f2b(cur.y);
        *(ushort2*)(sm + (t&1)*2048 + wbyte) = st;
        __syncthreads();
        const char* eb = sm + (t&1)*2048;
        bf16x8 a0, a1;
        {
            int row = ll;
            a0 = *(const bf16x8*)(eb + ((row*64 + lgp*16) ^ ((row&7)<<4)));
            row = 16 + ll;
            a1 = *(const bf16x8*)(eb + ((row*64 + lgp*16) ^ ((row&7)<<4)));
        }
        acc[0][0] = __builtin_amdgcn_mfma_f32_16x16x32_bf16(a0, cw0, acc[0][0],0,0,0);
        acc[0][1] = __builtin_amdgcn_mfma_f32_16x16x32_bf16(a0, cw1, acc[0][1],0,0,0);
        acc[1][0] = __builtin_amdgcn_mfma_f32_16x16x32_bf16(a1, cw0, acc[1][0],0,0,0);
        acc[1][1] = __builtin_amdgcn_mfma_f32_16x16x32_bf16(a1, cw1, acc[1][1],0,0,0);
        __syncthreads();
    }
    #pragma unroll
    for (int mi=0;mi<2;++mi){
        #pragma unroll
        for (int ni=0;ni<2;++ni){
            int col = w*32 + ni*16 + ll;
            f32x4 v = acc[mi][ni];
            #pragma unroll
            for (int rr=0;rr<4;++rr){
                int row = m0 + mi*16 + lgp*4 + rr;
                if (row < 50000) eprime[(long)row*256 + col] = f2b(v[rr]);
            }
        }
    }
}

// ---------------------------------------------------------------------------
// prep_k (r19 merge): blocks [0,8192) convert adj f32->bf16 (vectorized);
// blocks [8192,9792) build the 6 bf16 K-tiled weight blobs (zero-pad K).
// ---------------------------------------------------------------------------
__global__ __launch_bounds__(256) void prep_k(
    const float* __restrict__ adj, u16* __restrict__ adjb,
    const float* __restrict__ w1a, const float* __restrict__ w2a,
    const float* __restrict__ awa, const float* __restrict__ w1b,
    const float* __restrict__ w2b, const float* __restrict__ awb,
    u16* __restrict__ dst_base)
{
    if (blockIdx.x < 8192){
        long i = ((long)blockIdx.x*256 + threadIdx.x) * 4;
        if (i >= 2048L*4096L) return;
        float4 v = *(const float4*)(adj + i);
        *(ushort4*)(adjb + i) = pack4(v.x, v.y, v.z, v.w);
    } else {
        long idx = (long)(blockIdx.x - 8192)*256 + threadIdx.x;
        if (idx >= 81920L + 5L*65536L) return;
        const float* src; u16* dst; int Ksrc; long rem;
        if (idx < 81920L){ src = w1a; dst = dst_base; Ksrc = 300; rem = idx; }
        else {
            long j = (idx - 81920L) / 65536L, r2 = (idx - 81920L) % 65536L;
            src = (j==0)?w2a:(j==1)?awa:(j==2)?w1b:(j==3)?w2b:awb;
            dst = dst_base + 81920L + j*65536L; Ksrc = 256; rem = r2;
        }
        int k = (int)(rem >> 8), n = (int)(rem & 255);
        float v = (k < Ksrc) ? src[k*256 + n] : 0.f;
        int t = k>>5, kk = k&31;
        dst[((t*8 + (n>>5))<<10) + (n&31)*32 + kk] = f2b(v);
    }
}

// ---------------------------------------------------------------------------
// BatchNorm stats over rows of zb (2048 x 1024 bf16): scale/shift per column.
// ---------------------------------------------------------------------------
__global__ __launch_bounds__(256) void bnstats_k(
    const u16* __restrict__ zb, const float* __restrict__ gamma,
    const float* __restrict__ beta,
    float* __restrict__ scale, float* __restrict__ shift)
{
    const int tid = threadIdx.x;
    const int cl = tid & 3, ph = tid >> 2;
    const int c = blockIdx.x * 4 + cl;
    double s = 0.0, s2 = 0.0;
    #pragma unroll 8
    for (int r = ph; r < 2048; r += 64) {
        float v = b2f(zb[(long)r * 1024 + c]);
        s += v; s2 += (double)v * v;
    }
    __shared__ double ss[256], ss2[256];
    ss[tid] = s; ss2[tid] = s2;
    __syncthreads();
    for (int off = 128; off >= 4; off >>= 1){
        if (tid < off){ ss[tid] += ss[tid+off]; ss2[tid] += ss2[tid+off]; }
        __syncthreads();
    }
    if (tid < 4){
        int cc = blockIdx.x * 4 + tid;
        double mu = ss[tid] / 2048.0;
        double var = ss2[tid] / 2048.0 - mu * mu;
        float inv = (float)(1.0 / sqrt(var + 1e-5));
        float sc = gamma[cc] * inv;
        scale[cc] = sc;
        shift[cc] = beta[cc] - (float)mu * sc;
    }
}

// ---------------------------------------------------------------------------
// fc1 prep (merged): blocks [0,1024) build the bn-scaled bf16 weight blob;
// blocks [1024,1280) build the fused bias.
// ---------------------------------------------------------------------------
__global__ __launch_bounds__(256) void fc1prep_k(
    const float* __restrict__ fw, const float* __restrict__ scale,
    const float* __restrict__ shift, const float* __restrict__ fb,
    u16* __restrict__ dst, float* __restrict__ biasp)
{
    if (blockIdx.x < 1024){
        int lin = blockIdx.x*256 + threadIdx.x;           // 262144 total
        int c = lin >> 10, t = c >> 3, s = c & 7;
        int nl = (lin >> 5) & 31, kk = lin & 31;
        int n = s*32 + nl, k = t*32 + kk;
        dst[lin] = f2b(fw[k*256 + n] * scale[k]);
    } else {
        const int n = blockIdx.x - 1024, tid = threadIdx.x;
        float p = 0.f;
        #pragma unroll
        for (int i=0;i<4;++i){
            int k = tid + i*256;
            p += shift[k] * fw[k*256 + n];
        }
        __shared__ float red[256];
        red[tid] = p;
        __syncthreads();
        for (int off=128; off; off>>=1){
            if (tid < off) red[tid] += red[tid+off];
            __syncthreads();
        }
        if (tid == 0) biasp[n] = fb[n] + red[0];
    }
}

// ---------------------------------------------------------------------------
// fc1 MFMA (r19 regrid 4x64 = 256 blocks, full CU coverage):
// z2 = relu(zb @ W' + biasp). Block (h2,m): cols h2*64..+64, rows m*32..+32.
// Wave w: col-slab h2*2+(w&1), row-half (w>>1)*16. Staging unchanged.
// ---------------------------------------------------------------------------
__global__ __launch_bounds__(256) void fc1_mfma_k(
    const u16* __restrict__ zb, const u16* __restrict__ blob,
    const float* __restrict__ biasp, float* __restrict__ z2)
{
    __shared__ __align__(16) char sm[4096];     // 2 x 2KB A-tile dbuf
    const int h2 = blockIdx.x, m0 = blockIdx.y * 32;
    const int tid = threadIdx.x;
    const int w = tid>>6, l = tid&63, lgp = l>>4, ll = l&15;
    const f32x4 zero4 = {0.f,0.f,0.f,0.f};
    const int slab = h2*2 + (w & 1);     // 32-col slab 0..7
    const int rh   = w >> 1;             // row-half 0/1

    const int r  = tid >> 3;          // staging row 0..31
    const int kc = (tid & 7) * 4;     // k-chunk within 32
    const long arow = (long)(m0 + r) * 1024;
    const int wbyte = (r*64 + (tid&7)*8) ^ ((r&7)<<4);

    ushort4 pv = *(const ushort4*)(zb + arow + kc);
    const u16* chw = blob + (slab<<10) + ll*32 + lgp*8;
    bf16x8 w0 = *(const bf16x8*)(chw);
    bf16x8 w1 = *(const bf16x8*)(chw + 512);

    f32x4 acc0 = zero4, acc1 = zero4;   // ni = 0,1 for this wave's 16 rows

    #pragma unroll 4
    for (int t=0;t<32;++t){
        ushort4 cur = pv;
        bf16x8 cw0 = w0, cw1 = w1;
        if (t < 31){
            pv = *(const ushort4*)(zb + arow + (t+1)*32 + kc);
            const u16* nx = chw + (t+1)*8192;
            w0 = *(const bf16x8*)(nx);
            w1 = *(const bf16x8*)(nx + 512);
        }
        *(ushort4*)(sm + (t&1)*2048 + wbyte) = cur;
        __syncthreads();
        const char* eb = sm + (t&1)*2048;
        bf16x8 a;
        {
            int row = rh*16 + ll;
            a = *(const bf16x8*)(eb + ((row*64 + lgp*16) ^ ((row&7)<<4)));
        }
        acc0 = __builtin_amdgcn_mfma_f32_16x16x32_bf16(a, cw0, acc0,0,0,0);
        acc1 = __builtin_amdgcn_mfma_f32_16x16x32_bf16(a, cw1, acc1,0,0,0);
        __syncthreads();
    }
    #pragma unroll
    for (int ni=0;ni<2;++ni){
        int col = slab*32 + ni*16 + ll;
        float bv = biasp[col];
        f32x4 v = (ni==0) ? acc0 : acc1;
        #pragma unroll
        for (int rr=0;rr<4;++rr){
            int row = m0 + rh*16 + lgp*4 + rr;
            z2[(long)row*256 + col] = fmaxf(v[rr] + bv, 0.f);
        }
    }
}

// ---------------------------------------------------------------------------
// Segment attention + final head fused:
// z2 (128 x 16 x 256) -> pooled -> relu(@fc2+b2) -> @fc3+b3 -> log_softmax
// ---------------------------------------------------------------------------
__global__ __launch_bounds__(256) void sattfinal_k(
    const float* __restrict__ z2, const float* __restrict__ sw,
    const float* __restrict__ sb, const float* __restrict__ sv,
    const float* __restrict__ w2, const float* __restrict__ b2,
    const float* __restrict__ w3, const float* __restrict__ b3,
    float* __restrict__ out)
{
    const int b = blockIdx.x;
    const int tid = threadIdx.x;
    __shared__ float zs[16][256];
    for (int idx = tid; idx < 16 * 256; idx += 256) {
        int r = idx >> 8, c = idx & 255;
        zs[r][c] = z2[((long)b * 16 + r) * 256 + c];
    }
    __syncthreads();

    float acc[16] = {};
    for (int k = 0; k < 256; ++k) {
        float w = sw[k * 256 + tid];
        #pragma unroll
        for (int r = 0; r < 16; ++r) acc[r] += zs[r][k] * w;
    }
    const float sbv = sb[tid], svv = sv[tid];

    __shared__ float red[16][4];
    __shared__ float logit_s[16], alpha_s[16];
    const int warp = tid >> 6, lane = tid & 63;
    #pragma unroll
    for (int r = 0; r < 16; ++r) {
        float u = fmaxf(acc[r] + sbv, 0.f);
        float lv = u * svv;
        #pragma unroll
        for (int off = 32; off; off >>= 1) lv += __shfl_down(lv, off, 64);
        if (lane == 0) red[r][warp] = lv;
    }
    __syncthreads();
    if (tid < 16) logit_s[tid] = red[tid][0] + red[tid][1] + red[tid][2] + red[tid][3];
    __syncthreads();
    if (tid < 16) {
        float m = -INFINITY;
        #pragma unroll
        for (int i = 0; i < 16; ++i) m = fmaxf(m, logit_s[i]);
        float ssum = 0.f;
        #pragma unroll
        for (int i = 0; i < 16; ++i) ssum += expf(logit_s[i] - m);
        alpha_s[tid] = expf(logit_s[tid] - m) / ssum;
    }
    __syncthreads();
    float pacc = 0.f;
    #pragma unroll
    for (int r = 0; r < 16; ++r) pacc += alpha_s[r] * zs[r][tid];

    __shared__ float ps[256], z3s[128], z4s[10];
    ps[tid] = pacc;
    __syncthreads();
    if (tid < 128){
        float a2 = b2[tid];
        for (int k = 0; k < 256; ++k) a2 += ps[k] * w2[k * 128 + tid];
        z3s[tid] = fmaxf(a2, 0.f);
    }
    __syncthreads();
    if (tid < 10){
        float a3 = b3[tid];
        for (int k = 0; k < 128; ++k) a3 += z3s[k] * w3[k * 10 + tid];
        z4s[tid] = a3;
    }
    __syncthreads();
    if (tid < 10){
        float m = z4s[0];
        #pragma unroll
        for (int i = 1; i < 10; ++i) m = fmaxf(m, z4s[i]);
        float s = 0.f;
        #pragma unroll
        for (int i = 0; i < 10; ++i) s += expf(z4s[i] - m);
        out[b * 10 + tid] = z4s[tid] - m - logf(s);
    }
}

// ---------------------------------------------------------------------------
extern "C" void kernel_launch(void* const* d_in, const int* in_sizes, int n_in,
                              void* d_out, int out_size, void* d_ws, size_t ws_size,
                              hipStream_t stream)
{
    const int*   x      = (const int*)d_in[0];
    const float* adj    = (const float*)d_in[1];
    // d_in[2] = adj_s (unused), d_in[3]/d_in[4] = shape scalars
    const float* emb    = (const float*)d_in[5];
    const float* mp0_w1 = (const float*)d_in[6];
    const float* mp0_b1 = (const float*)d_in[7];
    const float* mp0_w2 = (const float*)d_in[8];
    const float* mp0_b2 = (const float*)d_in[9];
    const float* mp1_w1 = (const float*)d_in[10];
    const float* mp1_b1 = (const float*)d_in[11];
    const float* mp1_w2 = (const float*)d_in[12];
    const float* mp1_b2 = (const float*)d_in[13];
    const float* att0_w = (const float*)d_in[14];
    const float* att0_b = (const float*)d_in[15];
    const float* att0_v = (const float*)d_in[16];
    const float* att1_w = (const float*)d_in[17];
    const float* att1_b = (const float*)d_in[18];
    const float* att1_v = (const float*)d_in[19];
    const float* bn_g   = (const float*)d_in[20];
    const float* bn_b   = (const float*)d_in[21];
    const float* fc1_w  = (const float*)d_in[22];
    const float* fc1_b  = (const float*)d_in[23];
    const float* satt_w = (const float*)d_in[24];
    const float* satt_b = (const float*)d_in[25];
    const float* satt_v = (const float*)d_in[26];
    const float* fc2_w  = (const float*)d_in[27];
    const float* fc2_b  = (const float*)d_in[28];
    const float* fc3_w  = (const float*)d_in[29];
    const float* fc3_b  = (const float*)d_in[30];
    float* out = (float*)d_out;

    float* ws = (float*)d_ws;
    float* z2      = ws;                    // 2048*256 f32
    float* scale   = z2 + 2048L * 256;      // 1024
    float* shiftv  = scale + 1024;          // 1024
    float* biasp   = shiftv + 1024;         // 256
    u16*   wbase   = (u16*)(biasp + 256);
    u16* wb_w1a  = wbase;                   // 81920 u16 (K=320 tiled)
    u16* wb_w2a  = wb_w1a + 81920;          // 65536 each below
    u16* wb_awa  = wb_w2a + 65536;
    u16* wb_w1b  = wb_awa + 65536;
    u16* wb_w2b  = wb_w1b + 65536;
    u16* wb_awb  = wb_w2b + 65536;
    u16* adjb    = wb_awb + 65536;          // 2048*4096 u16 (16.8 MB)
    u16* zb      = adjb + 2048L*4096;       // 2048*1024 u16 (4.2 MB)
    u16* fc1blob = zb + 2048L*1024;         // 262144 u16
    u16* eprime  = fc1blob + 262144;        // 50048*256 u16 (25.6 MB)
    // total ws ~ 50 MB

    prep_k<<<dim3(9792), dim3(256), 0, stream>>>(
        adj, adjb, mp0_w1, mp0_w2, att0_w, mp1_w1, mp1_w2, att1_w, wbase);
    eprime_k<<<dim3(1563), dim3(512), 0, stream>>>(emb, wb_w1a, eprime);

    mega_k<<<dim3(1024), dim3(512), 0, stream>>>(
        x, adjb, eprime,
        wb_w2a, wb_awa, wb_w1b, wb_w2b, wb_awb,
        mp0_b1, mp0_b2, att0_b, att0_v,
        mp1_b1, mp1_b2, att1_b, att1_v, zb);

    bnstats_k<<<dim3(256), dim3(256), 0, stream>>>(zb, bn_g, bn_b, scale, shiftv);
    fc1prep_k<<<dim3(1280), dim3(256), 0, stream>>>(fc1_w, scale, shiftv, fc1_b,
        fc1blob, biasp);
    fc1_mfma_k<<<dim3(4, 64), dim3(256), 0, stream>>>(zb, fc1blob, biasp, z2);
    sattfinal_k<<<dim3(128), dim3(256), 0, stream>>>(z2, satt_w, satt_b, satt_v,
        fc2_w, fc2_b, fc3_w, fc3_b, out);
}